// Round 6
// baseline (146.769 us; speedup 1.0000x reference)
//
#include <hip/hip_runtime.h>
#include <cmath>

#define HW   16384
#define Wd   128
#define Hd   128
#define NB   4

typedef __attribute__((ext_vector_type(8))) short bf16x8;
typedef __attribute__((ext_vector_type(4))) float f32x4;
typedef __attribute__((ext_vector_type(4))) unsigned int u32x4;

__device__ inline unsigned short f2bf(float f) {
    unsigned u = __builtin_bit_cast(unsigned, f);
    unsigned r = (u + 0x7FFFu + ((u >> 16) & 1u)) >> 16;
    return (unsigned short)r;
}
__device__ inline float bflo(unsigned w) { return __builtin_bit_cast(float, w << 16); }
__device__ inline float bfhi(unsigned w) { return __builtin_bit_cast(float, w & 0xFFFF0000u); }

// ---------- weight repack into MFMA A-fragment-linear bf16 ----------
// dst: [9][4 m][KS][64 lane][8 e]; (k,m,ks,lane,e) <- w[oc][c][k], oc=m*16+(lane&15),
// c=ks*32+(lane>>4)*8+e; src1 for oc<Osplit else src2; zero-pad OOB.
__global__ void repack_mfma(const float* __restrict__ src1, const float* __restrict__ src2,
                            int Osplit, int O, int CIN, int KS, unsigned short* __restrict__ dst) {
    int idx = blockIdx.x * 256 + threadIdx.x;
    int total = 9 * 4 * KS * 64 * 8;
    if (idx >= total) return;
    int e    = idx & 7;
    int lane = (idx >> 3) & 63;
    int ks   = (idx >> 9) % KS;
    int m    = (idx / (512 * KS)) & 3;
    int k    = idx / (2048 * KS);
    int oc = m * 16 + (lane & 15);
    int c  = ks * 32 + (lane >> 4) * 8 + e;
    float v = 0.f;
    if (oc < O && c < CIN) {
        const float* s = (oc < Osplit) ? src1 + ((size_t)oc * CIN + c) * 9 + k
                                       : src2 + ((size_t)(oc - Osplit) * CIN + c) * 9 + k;
        v = *s;
    }
    dst[idx] = f2bf(v);
}

__global__ void bias_concat_kernel(const float* __restrict__ b1, const float* __restrict__ b2,
                                   float* __restrict__ dst) {
    int t = threadIdx.x;
    if (t < 27) dst[t] = b1[t];
    else if (t < 54) dst[t] = b2[t - 27];
}

// ---------- NCHW fp32 -> NHWC bf16, 16B-vectorized stores ----------
__global__ __launch_bounds__(256) void to_nhwc(const float* __restrict__ xin,
                                               const float* __restrict__ off,
                                               unsigned short* __restrict__ xn,
                                               unsigned short* __restrict__ offn) {
    int t = blockIdx.x * 256 + threadIdx.x;
    if (t < 65536) {
        int b = t >> 14, p = t & 16383;
        const float* s = xin + ((size_t)b * 64) * HW + p;
        unsigned short* d = xn + (size_t)t * 64;
#pragma unroll
        for (int g = 0; g < 8; g++) {
            unsigned short pk[8];
#pragma unroll
            for (int e = 0; e < 8; e++) pk[e] = f2bf(s[(size_t)(g * 8 + e) * HW]);
            *(bf16x8*)(d + g * 8) = *(bf16x8*)pk;
        }
    } else {
        int u = t - 65536;
        int b = u >> 14, p = u & 16383;
        const float* s = off + ((size_t)b * 32) * HW + p;
        unsigned short* d = offn + (size_t)u * 32;
#pragma unroll
        for (int g = 0; g < 4; g++) {
            unsigned short pk[8];
#pragma unroll
            for (int e = 0; e < 8; e++) pk[e] = f2bf(s[(size_t)(g * 8 + e) * HW]);
            *(bf16x8*)(d + g * 8) = *(bf16x8*)pk;
        }
    }
}

// ---------- small conv (CIN=32): unchanged 4-wave direct version ----------
template<int CIN, int OCT>
__global__ __launch_bounds__(256, 4) void conv_direct(
    const unsigned short* __restrict__ xn, const unsigned short* __restrict__ wf,
    const float* __restrict__ bias, float* __restrict__ out)
{
    constexpr int KS = CIN / 32;
    int lb = ((blockIdx.x & 7) << 7) | (blockIdx.x >> 3);   // XCD-chunked swizzle
    int t = threadIdx.x;
    int lane = t & 63, wv = t >> 6;
    int px = lb * 64 + wv * 16 + (lane & 15);
    int b = px >> 14, p = px & 16383;
    int row = p >> 7, col = p & 127;
    int cg = lane >> 4;

    const bf16x8* wfv = (const bf16x8*)wf;
    f32x4 acc[4];
#pragma unroll
    for (int m = 0; m < 4; m++) acc[m] = (f32x4){0.f, 0.f, 0.f, 0.f};

    auto loadB = [&](int k, bf16x8* bq) {
        int hh = row + k / 3 - 1, ww = col + k % 3 - 1;
        bool ok = (hh >= 0) & (hh < Hd) & (ww >= 0) & (ww < Wd);
        size_t base = ((size_t)(b << 14) + hh * Wd + ww) * CIN;
#pragma unroll
        for (int ks = 0; ks < KS; ks++) {
            bf16x8 v = (bf16x8){0, 0, 0, 0, 0, 0, 0, 0};
            if (ok) v = *(const bf16x8*)(xn + base + ks * 32 + cg * 8);
            bq[ks] = v;
        }
    };

    bf16x8 bq[KS];
    loadB(0, bq);

#pragma unroll
    for (int k = 0; k < 9; k++) {
        bf16x8 aF[4 * KS];
#pragma unroll
        for (int m = 0; m < 4; m++)
#pragma unroll
            for (int ks = 0; ks < KS; ks++)
                aF[m * KS + ks] = wfv[((k * 4 + m) * KS + ks) * 64 + lane];

        bf16x8 bn[KS];
        if (k < 8) loadB(k + 1, bn);

#pragma unroll
        for (int ks = 0; ks < KS; ks++)
#pragma unroll
            for (int m = 0; m < 4; m++)
                acc[m] = __builtin_amdgcn_mfma_f32_16x16x32_bf16(aF[m * KS + ks], bq[ks], acc[m], 0, 0, 0);

        if (k < 8) {
#pragma unroll
            for (int ks = 0; ks < KS; ks++) bq[ks] = bn[ks];
        }
    }

#pragma unroll
    for (int m = 0; m < 4; m++) {
        int ocb = m * 16 + cg * 4;
#pragma unroll
        for (int r = 0; r < 4; r++) {
            int oc = ocb + r;
            if (OCT == 64 || oc < OCT)
                out[((size_t)b * OCT + oc) * HW + p] = acc[m][r] + bias[oc];
        }
    }
}

// ---------- conv3x3 CIN=64, 8 waves, K-split (waves 0-3: c<32, 4-7: c>=32) ----------
__global__ __launch_bounds__(512, 8) void conv_direct2(
    const unsigned short* __restrict__ xn, const unsigned short* __restrict__ wf,
    const float* __restrict__ bias, float* __restrict__ out)
{
    __shared__ float red[16 * 256];   // [i(16)][wv(4)*64+lane] transposed, conflict-free
    int lb = ((blockIdx.x & 7) << 7) | (blockIdx.x >> 3);
    int t = threadIdx.x;
    int lane = t & 63;
    int wave = t >> 6;
    int kh = wave >> 2;               // K-half
    int wv = wave & 3;                // px quarter
    int px = lb * 64 + wv * 16 + (lane & 15);
    int b = px >> 14, p = px & 16383;
    int row = p >> 7, col = p & 127;
    int cg = lane >> 4;
    int c0 = kh * 32 + cg * 8;

    const bf16x8* wfv = (const bf16x8*)wf;
    f32x4 acc[4];
#pragma unroll
    for (int m = 0; m < 4; m++) acc[m] = (f32x4){0.f, 0.f, 0.f, 0.f};

    auto loadB = [&](int k) -> bf16x8 {
        int hh = row + k / 3 - 1, ww = col + k % 3 - 1;
        bool ok = (hh >= 0) & (hh < Hd) & (ww >= 0) & (ww < Wd);
        size_t base = ((size_t)(b << 14) + hh * Wd + ww) * 64;
        bf16x8 v = (bf16x8){0, 0, 0, 0, 0, 0, 0, 0};
        if (ok) v = *(const bf16x8*)(xn + base + c0);
        return v;
    };

    bf16x8 bq = loadB(0);
#pragma unroll
    for (int k = 0; k < 9; k++) {
        bf16x8 aF[4];
#pragma unroll
        for (int m = 0; m < 4; m++)
            aF[m] = wfv[((k * 4 + m) * 2 + kh) * 64 + lane];
        bf16x8 bn;
        if (k < 8) bn = loadB(k + 1);
#pragma unroll
        for (int m = 0; m < 4; m++)
            acc[m] = __builtin_amdgcn_mfma_f32_16x16x32_bf16(aF[m], bq, acc[m], 0, 0, 0);
        if (k < 8) bq = bn;
    }

    if (kh == 1) {
#pragma unroll
        for (int m = 0; m < 4; m++)
#pragma unroll
            for (int j = 0; j < 4; j++)
                red[(m * 4 + j) * 256 + wv * 64 + lane] = acc[m][j];
    }
    __syncthreads();
    if (kh == 0) {
#pragma unroll
        for (int m = 0; m < 4; m++) {
            int ocb = m * 16 + cg * 4;
#pragma unroll
            for (int r = 0; r < 4; r++) {
                int oc = ocb + r;
                float v = acc[m][r] + red[(m * 4 + r) * 256 + wv * 64 + lane] + bias[oc];
                out[((size_t)b * 64 + oc) * HW + p] = v;
            }
        }
    }
}

// ---------- DCNv2 sampling helpers ----------
struct Tap { float w00, w01, w10, w11; int o00, o01, o10, o11; };

__device__ inline Tap mkparams(float oy, float ox, float mv, int row, int col, int k) {
    Tap P;
    float mk = 1.f / (1.f + __expf(-mv));
    float ys = (float)(row + k / 3 - 1) + oy;
    float xs = (float)(col + k % 3 - 1) + ox;
    float y0f = floorf(ys), x0f = floorf(xs);
    float fy = ys - y0f, fx = xs - x0f;
    int y0 = (int)y0f, x0 = (int)x0f;
    int y1 = y0 + 1, x1 = x0 + 1;
    bool vy0 = (y0 >= 0) & (y0 < Hd);
    bool vy1 = (y1 >= 0) & (y1 < Hd);
    bool vx0 = (x0 >= 0) & (x0 < Wd);
    bool vx1 = (x1 >= 0) & (x1 < Wd);
    P.w00 = (vy0 && vx0) ? (1.f - fy) * (1.f - fx) * mk : 0.f;
    P.w01 = (vy0 && vx1) ? (1.f - fy) * fx * mk : 0.f;
    P.w10 = (vy1 && vx0) ? fy * (1.f - fx) * mk : 0.f;
    P.w11 = (vy1 && vx1) ? fy * fx * mk : 0.f;
    int iy0 = min(max(y0, 0), Hd - 1) * Wd;
    int iy1 = min(max(y1, 0), Hd - 1) * Wd;
    int ix0 = min(max(x0, 0), Wd - 1);
    int ix1 = min(max(x1, 0), Wd - 1);
    P.o00 = iy0 + ix0; P.o01 = iy0 + ix1; P.o10 = iy1 + ix0; P.o11 = iy1 + ix1;
    return P;
}

struct G4 { u32x4 a, b, c, d; };
__device__ inline G4 gather4(const unsigned short* __restrict__ xb, const Tap& P, int c0) {
    G4 g;
    g.a = *(const u32x4*)(xb + (size_t)P.o00 * 64 + c0);
    g.b = *(const u32x4*)(xb + (size_t)P.o01 * 64 + c0);
    g.c = *(const u32x4*)(xb + (size_t)P.o10 * 64 + c0);
    g.d = *(const u32x4*)(xb + (size_t)P.o11 * 64 + c0);
    return g;
}

__device__ inline bf16x8 combine4(const G4& g, const Tap& P) {
    unsigned ow[4];
#pragma unroll
    for (int wd = 0; wd < 4; wd++) {
        float slo = P.w00 * bflo(g.a[wd]);
        slo = fmaf(P.w01, bflo(g.b[wd]), slo);
        slo = fmaf(P.w10, bflo(g.c[wd]), slo);
        slo = fmaf(P.w11, bflo(g.d[wd]), slo);
        float shi = P.w00 * bfhi(g.a[wd]);
        shi = fmaf(P.w01, bfhi(g.b[wd]), shi);
        shi = fmaf(P.w10, bfhi(g.c[wd]), shi);
        shi = fmaf(P.w11, bfhi(g.d[wd]), shi);
        ow[wd] = (unsigned)f2bf(slo) | ((unsigned)f2bf(shi) << 16);
    }
    u32x4 r = {ow[0], ow[1], ow[2], ow[3]};
    return __builtin_bit_cast(bf16x8, r);
}

// ---------- DCNv2, 8 waves, K-split + LDS reduce ----------
// EPI 0: leaky -> outn (NHWC bf16). EPI 1: +resid(NCHW fp32) -> outn (NHWC bf16).
template<int EPI>
__global__ __launch_bounds__(512, 8) void dcn_direct2(
    const unsigned short* __restrict__ xn, const float* __restrict__ om, int omOff,
    const unsigned short* __restrict__ wf, const float* __restrict__ bias,
    const float* __restrict__ resid, unsigned short* __restrict__ outn)
{
    __shared__ float red[16 * 256];
    int lb = ((blockIdx.x & 7) << 7) | (blockIdx.x >> 3);
    int t = threadIdx.x;
    int lane = t & 63;
    int wave = t >> 6;
    int kh = wave >> 2;
    int wv = wave & 3;
    int px = lb * 64 + wv * 16 + (lane & 15);
    int b = px >> 14, p = px & 16383;
    int row = p >> 7, col = p & 127;
    int cg = lane >> 4;
    int c0 = kh * 32 + cg * 8;

    const float* omb = om + ((size_t)b * 54 + omOff) * HW + p;
    const unsigned short* xb = xn + ((size_t)(b << 14)) * 64;
    const bf16x8* wfv = (const bf16x8*)wf;

    f32x4 acc[4];
#pragma unroll
    for (int m = 0; m < 4; m++) acc[m] = (f32x4){0.f, 0.f, 0.f, 0.f};

    float o0y = omb[0], o0x = omb[(size_t)1 * HW], m0 = omb[(size_t)18 * HW];
    Tap P0 = mkparams(o0y, o0x, m0, row, col, 0);
    G4 GA = gather4(xb, P0, c0);

#pragma unroll
    for (int k = 0; k < 9; k++) {
        float n_oy = 0.f, n_ox = 0.f, n_mv = 0.f;
        if (k < 8) {
            n_oy = omb[(size_t)(2 * k + 2) * HW];
            n_ox = omb[(size_t)(2 * k + 3) * HW];
            n_mv = omb[(size_t)(19 + k) * HW];
        }
        bf16x8 aF[4];
#pragma unroll
        for (int m = 0; m < 4; m++)
            aF[m] = wfv[((k * 4 + m) * 2 + kh) * 64 + lane];

        bf16x8 bF = combine4(GA, P0);
#pragma unroll
        for (int m = 0; m < 4; m++)
            acc[m] = __builtin_amdgcn_mfma_f32_16x16x32_bf16(aF[m], bF, acc[m], 0, 0, 0);

        if (k < 8) {
            Tap P1 = mkparams(n_oy, n_ox, n_mv, row, col, k + 1);
            GA = gather4(xb, P1, c0);
            P0 = P1;
        }
    }

    if (kh == 1) {
#pragma unroll
        for (int m = 0; m < 4; m++)
#pragma unroll
            for (int j = 0; j < 4; j++)
                red[(m * 4 + j) * 256 + wv * 64 + lane] = acc[m][j];
    }
    __syncthreads();
    if (kh == 0) {
        unsigned short* drow = outn + (size_t)px * 64;
#pragma unroll
        for (int m = 0; m < 4; m++) {
            int ocb = m * 16 + cg * 4;
            unsigned short pk[4];
#pragma unroll
            for (int r = 0; r < 4; r++) {
                int oc = ocb + r;
                float v = acc[m][r] + red[(m * 4 + r) * 256 + wv * 64 + lane] + bias[oc];
                if (EPI == 0) v = (v >= 0.f) ? v : 0.01f * v;
                if (EPI == 1) v += resid[((size_t)b * 64 + oc) * HW + p];
                pk[r] = f2bf(v);
            }
            *(ushort4*)(drow + ocb) = *(ushort4*)pk;
        }
    }
}

extern "C" void kernel_launch(void* const* d_in, const int* in_sizes, int n_in,
                              void* d_out, int out_size, void* d_ws, size_t ws_size,
                              hipStream_t stream)
{
    const float* input  = (const float*)d_in[0];
    const float* offset = (const float*)d_in[1];
    const float* w_off1 = (const float*)d_in[2];
    const float* b_off1 = (const float*)d_in[3];
    const float* w1     = (const float*)d_in[4];
    const float* b1     = (const float*)d_in[5];
    const float* w_off2 = (const float*)d_in[6];
    const float* b_off2 = (const float*)d_in[7];
    const float* w2     = (const float*)d_in[8];
    const float* b2     = (const float*)d_in[9];
    const float* w_last = (const float*)d_in[10];
    const float* b_last = (const float*)d_in[11];
    float* out = (float*)d_out;

    float* ws = (float*)d_ws;
    float* om = ws;                                        // 3,538,944 f
    unsigned short* xn   = (unsigned short*)(om + 3538944);   // 4,194,304 ush
    unsigned short* offn = xn + 4194304;                   // 2,097,152 ush
    unsigned short* x1n  = offn + 2097152;                 // 4,194,304 ush
    unsigned short* x2n  = x1n + 4194304;                  // 4,194,304 ush
    unsigned short* wfo  = x2n + 4194304;                  // 18,432 ush
    unsigned short* wf1  = wfo + 18432;                    // 36,864 ush
    unsigned short* wf2  = wf1 + 36864;                    // 36,864 ush
    unsigned short* wfl  = wf2 + 36864;                    // 36,864 ush
    float* bias54 = (float*)(wfl + 36864);                 // 64 f

    repack_mfma<<<dim3(72),  256, 0, stream>>>(w_off1, w_off2, 27, 54, 32, 1, wfo);
    repack_mfma<<<dim3(144), 256, 0, stream>>>(w1, w1, 64, 64, 64, 2, wf1);
    repack_mfma<<<dim3(144), 256, 0, stream>>>(w2, w2, 64, 64, 64, 2, wf2);
    repack_mfma<<<dim3(144), 256, 0, stream>>>(w_last, w_last, 64, 64, 64, 2, wfl);
    bias_concat_kernel<<<dim3(1), 64, 0, stream>>>(b_off1, b_off2, bias54);

    // 131072 threads = 512 blocks (input 65536 px + offset 65536 px)
    to_nhwc<<<dim3(512), 256, 0, stream>>>(input, offset, xn, offn);

    // offset conv (54 oc) from NHWC offset -> om (NCHW fp32)
    conv_direct<32, 54><<<dim3(1024), 256, 0, stream>>>(offn, wfo, bias54, om);
    // DCN 1: sample xn, leaky -> x1n (NHWC bf16)
    dcn_direct2<0><<<dim3(1024), 512, 0, stream>>>(xn, om, 0, wf1, b1, nullptr, x1n);
    // DCN 2: sample x1n, + input residual -> x2n (NHWC bf16)
    dcn_direct2<1><<<dim3(1024), 512, 0, stream>>>(x1n, om, 27, wf2, b2, input, x2n);
    // final conv from x2n -> out (NCHW fp32)
    conv_direct2<<<dim3(1024), 512, 0, stream>>>(x2n, wfl, b_last, out);
}

// Round 7
// 146.119 us; speedup vs baseline: 1.0045x; 1.0045x over previous
//
#include <hip/hip_runtime.h>
#include <cmath>

#define HW   16384
#define Wd   128
#define Hd   128
#define NB   4

typedef __attribute__((ext_vector_type(8))) short bf16x8;
typedef __attribute__((ext_vector_type(4))) float f32x4;
typedef __attribute__((ext_vector_type(4))) unsigned int u32x4;

__device__ inline unsigned short f2bf(float f) {
    unsigned u = __builtin_bit_cast(unsigned, f);
    unsigned r = (u + 0x7FFFu + ((u >> 16) & 1u)) >> 16;
    return (unsigned short)r;
}
__device__ inline float bflo(unsigned w) { return __builtin_bit_cast(float, w << 16); }
__device__ inline float bfhi(unsigned w) { return __builtin_bit_cast(float, w & 0xFFFF0000u); }

// ---------- weight repack into MFMA A-fragment-linear bf16 ----------
// dst: [9][4 m][KS][64 lane][8 e]; (k,m,ks,lane,e) <- w[oc][c][k], oc=m*16+(lane&15),
// c=ks*32+(lane>>4)*8+e; src1 for oc<Osplit else src2; zero-pad OOB.
__global__ void repack_mfma(const float* __restrict__ src1, const float* __restrict__ src2,
                            int Osplit, int O, int CIN, int KS, unsigned short* __restrict__ dst) {
    int idx = blockIdx.x * 256 + threadIdx.x;
    int total = 9 * 4 * KS * 64 * 8;
    if (idx >= total) return;
    int e    = idx & 7;
    int lane = (idx >> 3) & 63;
    int ks   = (idx >> 9) % KS;
    int m    = (idx / (512 * KS)) & 3;
    int k    = idx / (2048 * KS);
    int oc = m * 16 + (lane & 15);
    int c  = ks * 32 + (lane >> 4) * 8 + e;
    float v = 0.f;
    if (oc < O && c < CIN) {
        const float* s = (oc < Osplit) ? src1 + ((size_t)oc * CIN + c) * 9 + k
                                       : src2 + ((size_t)(oc - Osplit) * CIN + c) * 9 + k;
        v = *s;
    }
    dst[idx] = f2bf(v);
}

__global__ void bias_concat_kernel(const float* __restrict__ b1, const float* __restrict__ b2,
                                   float* __restrict__ dst) {
    int t = threadIdx.x;
    if (t < 27) dst[t] = b1[t];
    else if (t < 54) dst[t] = b2[t - 27];
}

// ---------- NCHW fp32 -> NHWC bf16, 16B-vectorized stores ----------
__global__ __launch_bounds__(256) void to_nhwc(const float* __restrict__ xin,
                                               const float* __restrict__ off,
                                               unsigned short* __restrict__ xn,
                                               unsigned short* __restrict__ offn) {
    int t = blockIdx.x * 256 + threadIdx.x;
    if (t < 65536) {
        int b = t >> 14, p = t & 16383;
        const float* s = xin + ((size_t)b * 64) * HW + p;
        unsigned short* d = xn + (size_t)t * 64;
#pragma unroll
        for (int g = 0; g < 8; g++) {
            unsigned short pk[8];
#pragma unroll
            for (int e = 0; e < 8; e++) pk[e] = f2bf(s[(size_t)(g * 8 + e) * HW]);
            *(bf16x8*)(d + g * 8) = *(bf16x8*)pk;
        }
    } else {
        int u = t - 65536;
        int b = u >> 14, p = u & 16383;
        const float* s = off + ((size_t)b * 32) * HW + p;
        unsigned short* d = offn + (size_t)u * 32;
#pragma unroll
        for (int g = 0; g < 4; g++) {
            unsigned short pk[8];
#pragma unroll
            for (int e = 0; e < 8; e++) pk[e] = f2bf(s[(size_t)(g * 8 + e) * HW]);
            *(bf16x8*)(d + g * 8) = *(bf16x8*)pk;
        }
    }
}

// ---------- small conv (CIN=32): 4-wave direct version ----------
template<int CIN, int OCT>
__global__ __launch_bounds__(256, 4) void conv_direct(
    const unsigned short* __restrict__ xn, const unsigned short* __restrict__ wf,
    const float* __restrict__ bias, float* __restrict__ out)
{
    constexpr int KS = CIN / 32;
    int lb = ((blockIdx.x & 7) << 7) | (blockIdx.x >> 3);   // XCD-chunked swizzle
    int t = threadIdx.x;
    int lane = t & 63, wv = t >> 6;
    int px = lb * 64 + wv * 16 + (lane & 15);
    int b = px >> 14, p = px & 16383;
    int row = p >> 7, col = p & 127;
    int cg = lane >> 4;

    const bf16x8* wfv = (const bf16x8*)wf;
    f32x4 acc[4];
#pragma unroll
    for (int m = 0; m < 4; m++) acc[m] = (f32x4){0.f, 0.f, 0.f, 0.f};

    auto loadB = [&](int k, bf16x8* bq) {
        int hh = row + k / 3 - 1, ww = col + k % 3 - 1;
        bool ok = (hh >= 0) & (hh < Hd) & (ww >= 0) & (ww < Wd);
        size_t base = ((size_t)(b << 14) + hh * Wd + ww) * CIN;
#pragma unroll
        for (int ks = 0; ks < KS; ks++) {
            bf16x8 v = (bf16x8){0, 0, 0, 0, 0, 0, 0, 0};
            if (ok) v = *(const bf16x8*)(xn + base + ks * 32 + cg * 8);
            bq[ks] = v;
        }
    };

    bf16x8 bq[KS];
    loadB(0, bq);

#pragma unroll
    for (int k = 0; k < 9; k++) {
        bf16x8 aF[4 * KS];
#pragma unroll
        for (int m = 0; m < 4; m++)
#pragma unroll
            for (int ks = 0; ks < KS; ks++)
                aF[m * KS + ks] = wfv[((k * 4 + m) * KS + ks) * 64 + lane];

        bf16x8 bn[KS];
        if (k < 8) loadB(k + 1, bn);

#pragma unroll
        for (int ks = 0; ks < KS; ks++)
#pragma unroll
            for (int m = 0; m < 4; m++)
                acc[m] = __builtin_amdgcn_mfma_f32_16x16x32_bf16(aF[m * KS + ks], bq[ks], acc[m], 0, 0, 0);

        if (k < 8) {
#pragma unroll
            for (int ks = 0; ks < KS; ks++) bq[ks] = bn[ks];
        }
    }

#pragma unroll
    for (int m = 0; m < 4; m++) {
        int ocb = m * 16 + cg * 4;
#pragma unroll
        for (int r = 0; r < 4; r++) {
            int oc = ocb + r;
            if (OCT == 64 || oc < OCT)
                out[((size_t)b * OCT + oc) * HW + p] = acc[m][r] + bias[oc];
        }
    }
}

// ---------- conv3x3 CIN=64, 8 waves, K-split (waves 0-3: c<32, 4-7: c>=32) ----------
__global__ __launch_bounds__(512, 8) void conv_direct2(
    const unsigned short* __restrict__ xn, const unsigned short* __restrict__ wf,
    const float* __restrict__ bias, float* __restrict__ out)
{
    __shared__ float red[16 * 256];   // [i(16)][wv(4)*64+lane] transposed, conflict-free
    int lb = ((blockIdx.x & 7) << 7) | (blockIdx.x >> 3);
    int t = threadIdx.x;
    int lane = t & 63;
    int wave = t >> 6;
    int kh = wave >> 2;               // K-half
    int wv = wave & 3;                // px quarter
    int px = lb * 64 + wv * 16 + (lane & 15);
    int b = px >> 14, p = px & 16383;
    int row = p >> 7, col = p & 127;
    int cg = lane >> 4;
    int c0 = kh * 32 + cg * 8;

    const bf16x8* wfv = (const bf16x8*)wf;
    f32x4 acc[4];
#pragma unroll
    for (int m = 0; m < 4; m++) acc[m] = (f32x4){0.f, 0.f, 0.f, 0.f};

    auto loadB = [&](int k) -> bf16x8 {
        int hh = row + k / 3 - 1, ww = col + k % 3 - 1;
        bool ok = (hh >= 0) & (hh < Hd) & (ww >= 0) & (ww < Wd);
        size_t base = ((size_t)(b << 14) + hh * Wd + ww) * 64;
        bf16x8 v = (bf16x8){0, 0, 0, 0, 0, 0, 0, 0};
        if (ok) v = *(const bf16x8*)(xn + base + c0);
        return v;
    };

    bf16x8 bq = loadB(0);
#pragma unroll
    for (int k = 0; k < 9; k++) {
        bf16x8 aF[4];
#pragma unroll
        for (int m = 0; m < 4; m++)
            aF[m] = wfv[((k * 4 + m) * 2 + kh) * 64 + lane];
        bf16x8 bn;
        if (k < 8) bn = loadB(k + 1);
#pragma unroll
        for (int m = 0; m < 4; m++)
            acc[m] = __builtin_amdgcn_mfma_f32_16x16x32_bf16(aF[m], bq, acc[m], 0, 0, 0);
        if (k < 8) bq = bn;
    }

    if (kh == 1) {
#pragma unroll
        for (int m = 0; m < 4; m++)
#pragma unroll
            for (int j = 0; j < 4; j++)
                red[(m * 4 + j) * 256 + wv * 64 + lane] = acc[m][j];
    }
    __syncthreads();
    if (kh == 0) {
#pragma unroll
        for (int m = 0; m < 4; m++) {
            int ocb = m * 16 + cg * 4;
#pragma unroll
            for (int r = 0; r < 4; r++) {
                int oc = ocb + r;
                float v = acc[m][r] + red[(m * 4 + r) * 256 + wv * 64 + lane] + bias[oc];
                out[((size_t)b * 64 + oc) * HW + p] = v;
            }
        }
    }
}

// ---------- DCNv2 sampling helpers ----------
struct Tap { float w00, w01, w10, w11; int o00, o01, o10, o11; };

__device__ inline Tap mkparams(float oy, float ox, float mv, int row, int col, int k) {
    Tap P;
    float mk = 1.f / (1.f + __expf(-mv));
    float ys = (float)(row + k / 3 - 1) + oy;
    float xs = (float)(col + k % 3 - 1) + ox;
    float y0f = floorf(ys), x0f = floorf(xs);
    float fy = ys - y0f, fx = xs - x0f;
    int y0 = (int)y0f, x0 = (int)x0f;
    int y1 = y0 + 1, x1 = x0 + 1;
    bool vy0 = (y0 >= 0) & (y0 < Hd);
    bool vy1 = (y1 >= 0) & (y1 < Hd);
    bool vx0 = (x0 >= 0) & (x0 < Wd);
    bool vx1 = (x1 >= 0) & (x1 < Wd);
    P.w00 = (vy0 && vx0) ? (1.f - fy) * (1.f - fx) * mk : 0.f;
    P.w01 = (vy0 && vx1) ? (1.f - fy) * fx * mk : 0.f;
    P.w10 = (vy1 && vx0) ? fy * (1.f - fx) * mk : 0.f;
    P.w11 = (vy1 && vx1) ? fy * fx * mk : 0.f;
    int iy0 = min(max(y0, 0), Hd - 1) * Wd;
    int iy1 = min(max(y1, 0), Hd - 1) * Wd;
    int ix0 = min(max(x0, 0), Wd - 1);
    int ix1 = min(max(x1, 0), Wd - 1);
    P.o00 = iy0 + ix0; P.o01 = iy0 + ix1; P.o10 = iy1 + ix0; P.o11 = iy1 + ix1;
    return P;
}

struct G4 { u32x4 a, b, c, d; };
__device__ inline G4 gather4(const unsigned short* __restrict__ xb, const Tap& P, int c0) {
    G4 g;
    g.a = *(const u32x4*)(xb + (size_t)P.o00 * 64 + c0);
    g.b = *(const u32x4*)(xb + (size_t)P.o01 * 64 + c0);
    g.c = *(const u32x4*)(xb + (size_t)P.o10 * 64 + c0);
    g.d = *(const u32x4*)(xb + (size_t)P.o11 * 64 + c0);
    return g;
}

__device__ inline bf16x8 combine4(const G4& g, const Tap& P) {
    unsigned ow[4];
#pragma unroll
    for (int wd = 0; wd < 4; wd++) {
        float slo = P.w00 * bflo(g.a[wd]);
        slo = fmaf(P.w01, bflo(g.b[wd]), slo);
        slo = fmaf(P.w10, bflo(g.c[wd]), slo);
        slo = fmaf(P.w11, bflo(g.d[wd]), slo);
        float shi = P.w00 * bfhi(g.a[wd]);
        shi = fmaf(P.w01, bfhi(g.b[wd]), shi);
        shi = fmaf(P.w10, bfhi(g.c[wd]), shi);
        shi = fmaf(P.w11, bfhi(g.d[wd]), shi);
        ow[wd] = (unsigned)f2bf(slo) | ((unsigned)f2bf(shi) << 16);
    }
    u32x4 r = {ow[0], ow[1], ow[2], ow[3]};
    return __builtin_bit_cast(bf16x8, r);
}

// ---------- DCNv2, 8 waves, K-split, LDS-precomputed Taps (no spill: 80 VGPR budget) ----------
// EPI 0: leaky -> outn (NHWC bf16). EPI 1: +resid(NCHW fp32) -> outn (NHWC bf16).
template<int EPI>
__global__ __launch_bounds__(512, 6) void dcn_direct3(
    const unsigned short* __restrict__ xn, const float* __restrict__ om, int omOff,
    const unsigned short* __restrict__ wf, const float* __restrict__ bias,
    const float* __restrict__ resid, unsigned short* __restrict__ outn)
{
    __shared__ float tw[4][576];   // corner weights, SoA [corner][k*64+sp]
    __shared__ int   tو_pad;       // (avoid name clash)
    __shared__ int   tof[4][576];  // corner offsets (px index)
    __shared__ float red[16 * 256];

    int lb = ((blockIdx.x & 7) << 7) | (blockIdx.x >> 3);
    int t = threadIdx.x;
    int pxbase = lb * 64;
    int b = pxbase >> 14;

    // ---- phase 1: precompute all 576 tap params (once per block, deduped across kh) ----
    for (int s = t; s < 576; s += 512) {
        int k = s >> 6, sp = s & 63;
        int p = (pxbase & 16383) + sp;
        int row = p >> 7, col = p & 127;
        const float* omb = om + ((size_t)b * 54 + omOff) * HW + p;
        float oy = omb[(size_t)(2 * k) * HW];
        float ox = omb[(size_t)(2 * k + 1) * HW];
        float mv = omb[(size_t)(18 + k) * HW];
        Tap P = mkparams(oy, ox, mv, row, col, k);
        tw[0][s] = P.w00; tw[1][s] = P.w01; tw[2][s] = P.w10; tw[3][s] = P.w11;
        tof[0][s] = P.o00; tof[1][s] = P.o01; tof[2][s] = P.o10; tof[3][s] = P.o11;
    }
    __syncthreads();

    int lane = t & 63;
    int wave = t >> 6;
    int kh = wave >> 2;
    int wv = wave & 3;
    int sp = wv * 16 + (lane & 15);
    int px = pxbase + sp;
    int p = px & 16383;
    int cg = lane >> 4;
    int c0 = kh * 32 + cg * 8;

    const unsigned short* xb = xn + ((size_t)(b << 14)) * 64;
    const bf16x8* wfv = (const bf16x8*)wf;

    f32x4 acc[4];
#pragma unroll
    for (int m = 0; m < 4; m++) acc[m] = (f32x4){0.f, 0.f, 0.f, 0.f};

#pragma unroll
    for (int k = 0; k < 9; k++) {
        int s = k * 64 + sp;
        Tap P;
        P.w00 = tw[0][s]; P.w01 = tw[1][s]; P.w10 = tw[2][s]; P.w11 = tw[3][s];
        P.o00 = tof[0][s]; P.o01 = tof[1][s]; P.o10 = tof[2][s]; P.o11 = tof[3][s];

        G4 G = gather4(xb, P, c0);

        bf16x8 aF[4];
#pragma unroll
        for (int m = 0; m < 4; m++)
            aF[m] = wfv[((k * 4 + m) * 2 + kh) * 64 + lane];

        bf16x8 bF = combine4(G, P);
#pragma unroll
        for (int m = 0; m < 4; m++)
            acc[m] = __builtin_amdgcn_mfma_f32_16x16x32_bf16(aF[m], bF, acc[m], 0, 0, 0);
    }

    if (kh == 1) {
#pragma unroll
        for (int m = 0; m < 4; m++)
#pragma unroll
            for (int j = 0; j < 4; j++)
                red[(m * 4 + j) * 256 + wv * 64 + lane] = acc[m][j];
    }
    __syncthreads();
    if (kh == 0) {
        unsigned short* drow = outn + (size_t)px * 64;
#pragma unroll
        for (int m = 0; m < 4; m++) {
            int ocb = m * 16 + cg * 4;
            unsigned short pk[4];
#pragma unroll
            for (int r = 0; r < 4; r++) {
                int oc = ocb + r;
                float v = acc[m][r] + red[(m * 4 + r) * 256 + wv * 64 + lane] + bias[oc];
                if (EPI == 0) v = (v >= 0.f) ? v : 0.01f * v;
                if (EPI == 1) v += resid[((size_t)b * 64 + oc) * HW + p];
                pk[r] = f2bf(v);
            }
            *(ushort4*)(drow + ocb) = *(ushort4*)pk;
        }
    }
}

extern "C" void kernel_launch(void* const* d_in, const int* in_sizes, int n_in,
                              void* d_out, int out_size, void* d_ws, size_t ws_size,
                              hipStream_t stream)
{
    const float* input  = (const float*)d_in[0];
    const float* offset = (const float*)d_in[1];
    const float* w_off1 = (const float*)d_in[2];
    const float* b_off1 = (const float*)d_in[3];
    const float* w1     = (const float*)d_in[4];
    const float* b1     = (const float*)d_in[5];
    const float* w_off2 = (const float*)d_in[6];
    const float* b_off2 = (const float*)d_in[7];
    const float* w2     = (const float*)d_in[8];
    const float* b2     = (const float*)d_in[9];
    const float* w_last = (const float*)d_in[10];
    const float* b_last = (const float*)d_in[11];
    float* out = (float*)d_out;

    float* ws = (float*)d_ws;
    float* om = ws;                                        // 3,538,944 f
    unsigned short* xn   = (unsigned short*)(om + 3538944);   // 4,194,304 ush
    unsigned short* offn = xn + 4194304;                   // 2,097,152 ush
    unsigned short* x1n  = offn + 2097152;                 // 4,194,304 ush
    unsigned short* x2n  = x1n + 4194304;                  // 4,194,304 ush
    unsigned short* wfo  = x2n + 4194304;                  // 18,432 ush
    unsigned short* wf1  = wfo + 18432;                    // 36,864 ush
    unsigned short* wf2  = wf1 + 36864;                    // 36,864 ush
    unsigned short* wfl  = wf2 + 36864;                    // 36,864 ush
    float* bias54 = (float*)(wfl + 36864);                 // 64 f

    repack_mfma<<<dim3(72),  256, 0, stream>>>(w_off1, w_off2, 27, 54, 32, 1, wfo);
    repack_mfma<<<dim3(144), 256, 0, stream>>>(w1, w1, 64, 64, 64, 2, wf1);
    repack_mfma<<<dim3(144), 256, 0, stream>>>(w2, w2, 64, 64, 64, 2, wf2);
    repack_mfma<<<dim3(144), 256, 0, stream>>>(w_last, w_last, 64, 64, 64, 2, wfl);
    bias_concat_kernel<<<dim3(1), 64, 0, stream>>>(b_off1, b_off2, bias54);

    // 131072 threads = 512 blocks (input 65536 px + offset 65536 px)
    to_nhwc<<<dim3(512), 256, 0, stream>>>(input, offset, xn, offn);

    // offset conv (54 oc) from NHWC offset -> om (NCHW fp32)
    conv_direct<32, 54><<<dim3(1024), 256, 0, stream>>>(offn, wfo, bias54, om);
    // DCN 1: sample xn, leaky -> x1n (NHWC bf16)
    dcn_direct3<0><<<dim3(1024), 512, 0, stream>>>(xn, om, 0, wf1, b1, nullptr, x1n);
    // DCN 2: sample x1n, + input residual -> x2n (NHWC bf16)
    dcn_direct3<1><<<dim3(1024), 512, 0, stream>>>(x1n, om, 27, wf2, b2, input, x2n);
    // final conv from x2n -> out (NCHW fp32)
    conv_direct2<<<dim3(1024), 512, 0, stream>>>(x2n, wfl, b_last, out);
}

// Round 8
// 122.676 us; speedup vs baseline: 1.1964x; 1.1911x over previous
//
#include <hip/hip_runtime.h>
#include <cmath>

#define HW   16384
#define Wd   128
#define Hd   128
#define NB   4

typedef __attribute__((ext_vector_type(8))) short bf16x8;
typedef __attribute__((ext_vector_type(4))) float f32x4;
typedef __attribute__((ext_vector_type(4))) unsigned int u32x4;

__device__ inline unsigned short f2bf(float f) {
    unsigned u = __builtin_bit_cast(unsigned, f);
    unsigned r = (u + 0x7FFFu + ((u >> 16) & 1u)) >> 16;
    return (unsigned short)r;
}
__device__ inline float bflo(unsigned w) { return __builtin_bit_cast(float, w << 16); }
__device__ inline float bfhi(unsigned w) { return __builtin_bit_cast(float, w & 0xFFFF0000u); }

// ---------- weight repack into MFMA A-fragment-linear bf16 ----------
__global__ void repack_mfma(const float* __restrict__ src1, const float* __restrict__ src2,
                            int Osplit, int O, int CIN, int KS, unsigned short* __restrict__ dst) {
    int idx = blockIdx.x * 256 + threadIdx.x;
    int total = 9 * 4 * KS * 64 * 8;
    if (idx >= total) return;
    int e    = idx & 7;
    int lane = (idx >> 3) & 63;
    int ks   = (idx >> 9) % KS;
    int m    = (idx / (512 * KS)) & 3;
    int k    = idx / (2048 * KS);
    int oc = m * 16 + (lane & 15);
    int c  = ks * 32 + (lane >> 4) * 8 + e;
    float v = 0.f;
    if (oc < O && c < CIN) {
        const float* s = (oc < Osplit) ? src1 + ((size_t)oc * CIN + c) * 9 + k
                                       : src2 + ((size_t)(oc - Osplit) * CIN + c) * 9 + k;
        v = *s;
    }
    dst[idx] = f2bf(v);
}

__global__ void bias_concat_kernel(const float* __restrict__ b1, const float* __restrict__ b2,
                                   float* __restrict__ dst) {
    int t = threadIdx.x;
    if (t < 27) dst[t] = b1[t];
    else if (t < 54) dst[t] = b2[t - 27];
}

// ---------- NCHW fp32 -> NHWC bf16, 16B-vectorized stores ----------
__global__ __launch_bounds__(256) void to_nhwc(const float* __restrict__ xin,
                                               const float* __restrict__ off,
                                               unsigned short* __restrict__ xn,
                                               unsigned short* __restrict__ offn) {
    int t = blockIdx.x * 256 + threadIdx.x;
    if (t < 65536) {
        int b = t >> 14, p = t & 16383;
        const float* s = xin + ((size_t)b * 64) * HW + p;
        unsigned short* d = xn + (size_t)t * 64;
#pragma unroll
        for (int g = 0; g < 8; g++) {
            unsigned short pk[8];
#pragma unroll
            for (int e = 0; e < 8; e++) pk[e] = f2bf(s[(size_t)(g * 8 + e) * HW]);
            *(bf16x8*)(d + g * 8) = *(bf16x8*)pk;
        }
    } else {
        int u = t - 65536;
        int b = u >> 14, p = u & 16383;
        const float* s = off + ((size_t)b * 32) * HW + p;
        unsigned short* d = offn + (size_t)u * 32;
#pragma unroll
        for (int g = 0; g < 4; g++) {
            unsigned short pk[8];
#pragma unroll
            for (int e = 0; e < 8; e++) pk[e] = f2bf(s[(size_t)(g * 8 + e) * HW]);
            *(bf16x8*)(d + g * 8) = *(bf16x8*)pk;
        }
    }
}

// ---------- small conv (CIN=32): 4-wave direct version ----------
template<int CIN, int OCT>
__global__ __launch_bounds__(256, 4) void conv_direct(
    const unsigned short* __restrict__ xn, const unsigned short* __restrict__ wf,
    const float* __restrict__ bias, float* __restrict__ out)
{
    constexpr int KS = CIN / 32;
    int lb = ((blockIdx.x & 7) << 7) | (blockIdx.x >> 3);
    int t = threadIdx.x;
    int lane = t & 63, wv = t >> 6;
    int px = lb * 64 + wv * 16 + (lane & 15);
    int b = px >> 14, p = px & 16383;
    int row = p >> 7, col = p & 127;
    int cg = lane >> 4;

    const bf16x8* wfv = (const bf16x8*)wf;
    f32x4 acc[4];
#pragma unroll
    for (int m = 0; m < 4; m++) acc[m] = (f32x4){0.f, 0.f, 0.f, 0.f};

    auto loadB = [&](int k, bf16x8* bq) {
        int hh = row + k / 3 - 1, ww = col + k % 3 - 1;
        bool ok = (hh >= 0) & (hh < Hd) & (ww >= 0) & (ww < Wd);
        size_t base = ((size_t)(b << 14) + hh * Wd + ww) * CIN;
#pragma unroll
        for (int ks = 0; ks < KS; ks++) {
            bf16x8 v = (bf16x8){0, 0, 0, 0, 0, 0, 0, 0};
            if (ok) v = *(const bf16x8*)(xn + base + ks * 32 + cg * 8);
            bq[ks] = v;
        }
    };

    bf16x8 bq[KS];
    loadB(0, bq);

#pragma unroll
    for (int k = 0; k < 9; k++) {
        bf16x8 aF[4 * KS];
#pragma unroll
        for (int m = 0; m < 4; m++)
#pragma unroll
            for (int ks = 0; ks < KS; ks++)
                aF[m * KS + ks] = wfv[((k * 4 + m) * KS + ks) * 64 + lane];

        bf16x8 bn[KS];
        if (k < 8) loadB(k + 1, bn);

#pragma unroll
        for (int ks = 0; ks < KS; ks++)
#pragma unroll
            for (int m = 0; m < 4; m++)
                acc[m] = __builtin_amdgcn_mfma_f32_16x16x32_bf16(aF[m * KS + ks], bq[ks], acc[m], 0, 0, 0);

        if (k < 8) {
#pragma unroll
            for (int ks = 0; ks < KS; ks++) bq[ks] = bn[ks];
        }
    }

#pragma unroll
    for (int m = 0; m < 4; m++) {
        int ocb = m * 16 + cg * 4;
#pragma unroll
        for (int r = 0; r < 4; r++) {
            int oc = ocb + r;
            if (OCT == 64 || oc < OCT)
                out[((size_t)b * OCT + oc) * HW + p] = acc[m][r] + bias[oc];
        }
    }
}

// ---------- conv3x3 CIN=64, 8 waves, K-split ----------
__global__ __launch_bounds__(512, 8) void conv_direct2(
    const unsigned short* __restrict__ xn, const unsigned short* __restrict__ wf,
    const float* __restrict__ bias, float* __restrict__ out)
{
    __shared__ float red[16 * 256];
    int lb = ((blockIdx.x & 7) << 7) | (blockIdx.x >> 3);
    int t = threadIdx.x;
    int lane = t & 63;
    int wave = t >> 6;
    int kh = wave >> 2;
    int wv = wave & 3;
    int px = lb * 64 + wv * 16 + (lane & 15);
    int b = px >> 14, p = px & 16383;
    int row = p >> 7, col = p & 127;
    int cg = lane >> 4;
    int c0 = kh * 32 + cg * 8;

    const bf16x8* wfv = (const bf16x8*)wf;
    f32x4 acc[4];
#pragma unroll
    for (int m = 0; m < 4; m++) acc[m] = (f32x4){0.f, 0.f, 0.f, 0.f};

    auto loadB = [&](int k) -> bf16x8 {
        int hh = row + k / 3 - 1, ww = col + k % 3 - 1;
        bool ok = (hh >= 0) & (hh < Hd) & (ww >= 0) & (ww < Wd);
        size_t base = ((size_t)(b << 14) + hh * Wd + ww) * 64;
        bf16x8 v = (bf16x8){0, 0, 0, 0, 0, 0, 0, 0};
        if (ok) v = *(const bf16x8*)(xn + base + c0);
        return v;
    };

    bf16x8 bq = loadB(0);
#pragma unroll
    for (int k = 0; k < 9; k++) {
        bf16x8 aF[4];
#pragma unroll
        for (int m = 0; m < 4; m++)
            aF[m] = wfv[((k * 4 + m) * 2 + kh) * 64 + lane];
        bf16x8 bn;
        if (k < 8) bn = loadB(k + 1);
#pragma unroll
        for (int m = 0; m < 4; m++)
            acc[m] = __builtin_amdgcn_mfma_f32_16x16x32_bf16(aF[m], bq, acc[m], 0, 0, 0);
        if (k < 8) bq = bn;
    }

    if (kh == 1) {
#pragma unroll
        for (int m = 0; m < 4; m++)
#pragma unroll
            for (int j = 0; j < 4; j++)
                red[(m * 4 + j) * 256 + wv * 64 + lane] = acc[m][j];
    }
    __syncthreads();
    if (kh == 0) {
#pragma unroll
        for (int m = 0; m < 4; m++) {
            int ocb = m * 16 + cg * 4;
#pragma unroll
            for (int r = 0; r < 4; r++) {
                int oc = ocb + r;
                float v = acc[m][r] + red[(m * 4 + r) * 256 + wv * 64 + lane] + bias[oc];
                out[((size_t)b * 64 + oc) * HW + p] = v;
            }
        }
    }
}

// ---------- DCNv2 sampling helpers ----------
struct Tap { float w00, w01, w10, w11; int o00, o01, o10, o11; };

__device__ inline Tap mkparams(float oy, float ox, float mv, int row, int col, int k) {
    Tap P;
    float mk = 1.f / (1.f + __expf(-mv));
    float ys = (float)(row + k / 3 - 1) + oy;
    float xs = (float)(col + k % 3 - 1) + ox;
    float y0f = floorf(ys), x0f = floorf(xs);
    float fy = ys - y0f, fx = xs - x0f;
    int y0 = (int)y0f, x0 = (int)x0f;
    int y1 = y0 + 1, x1 = x0 + 1;
    bool vy0 = (y0 >= 0) & (y0 < Hd);
    bool vy1 = (y1 >= 0) & (y1 < Hd);
    bool vx0 = (x0 >= 0) & (x0 < Wd);
    bool vx1 = (x1 >= 0) & (x1 < Wd);
    P.w00 = (vy0 && vx0) ? (1.f - fy) * (1.f - fx) * mk : 0.f;
    P.w01 = (vy0 && vx1) ? (1.f - fy) * fx * mk : 0.f;
    P.w10 = (vy1 && vx0) ? fy * (1.f - fx) * mk : 0.f;
    P.w11 = (vy1 && vx1) ? fy * fx * mk : 0.f;
    int iy0 = min(max(y0, 0), Hd - 1) * Wd;
    int iy1 = min(max(y1, 0), Hd - 1) * Wd;
    int ix0 = min(max(x0, 0), Wd - 1);
    int ix1 = min(max(x1, 0), Wd - 1);
    P.o00 = iy0 + ix0; P.o01 = iy0 + ix1; P.o10 = iy1 + ix0; P.o11 = iy1 + ix1;
    return P;
}

// ---------- DCNv2, LDS-staged sampling window ----------
// Window: 7 rows x 70 cols around the block's 64 px (covers |off|<2; ~5.9 sigma).
// Per-lane gathers become swizzled ds_read_b128; rare out-of-window lanes fall
// back to a predicated global load (correctness only, ~never executes).
// EPI 0: leaky -> outn (NHWC bf16). EPI 1: +resid(NCHW fp32) -> outn (NHWC bf16).
template<int EPI>
__global__ __launch_bounds__(512, 4) void dcn_stage(
    const unsigned short* __restrict__ xn, const float* __restrict__ om, int omOff,
    const unsigned short* __restrict__ wf, const float* __restrict__ bias,
    const float* __restrict__ resid, unsigned short* __restrict__ outn)
{
    __shared__ __align__(16) unsigned short stage[490 * 64];  // 7*70 px-slots x 64ch = 62.7KB
    __shared__ float tw[4][576];                              // 9.2KB corner weights
    __shared__ unsigned short tof[4][576];                    // 4.6KB corner pixel idx

    int lb = ((blockIdx.x & 7) << 7) | (blockIdx.x >> 3);
    int t = threadIdx.x;
    int pxbase = lb * 64;
    int b = pxbase >> 14;
    int pbase = pxbase & 16383;
    int rowbase = pbase >> 7;
    int colbase = pbase & 127;          // 0 or 64
    int ybase = rowbase - 3;
    int xbase = colbase - 3;
    const unsigned short* xb = xn + ((size_t)(b << 14)) * 64;

    // ---- phase 1a: tap params (576 = 9 taps x 64 px) ----
    for (int s = t; s < 576; s += 512) {
        int k = s >> 6, sp = s & 63;
        int p = pbase + sp;
        int row = p >> 7, col = p & 127;
        const float* omb = om + ((size_t)b * 54 + omOff) * HW + p;
        float oy = omb[(size_t)(2 * k) * HW];
        float ox = omb[(size_t)(2 * k + 1) * HW];
        float mv = omb[(size_t)(18 + k) * HW];
        Tap P = mkparams(oy, ox, mv, row, col, k);
        tw[0][s] = P.w00; tw[1][s] = P.w01; tw[2][s] = P.w10; tw[3][s] = P.w11;
        tof[0][s] = (unsigned short)P.o00; tof[1][s] = (unsigned short)P.o01;
        tof[2][s] = (unsigned short)P.o10; tof[3][s] = (unsigned short)P.o11;
    }
    // ---- phase 1b: stage fill, coalesced, chunk-swizzled (slot j' = j ^ (ps&7)) ----
    for (int q = t; q < 3920; q += 512) {     // 490 slots * 8 chunks
        int ps = q >> 3, j = q & 7;
        int ly = ps / 70, lx = ps - ly * 70;
        int y = min(max(ybase + ly, 0), Hd - 1);
        int x = min(max(xbase + lx, 0), Wd - 1);
        u32x4 v = *(const u32x4*)(xb + ((size_t)(y * Wd + x)) * 64 + j * 8);
        *(u32x4*)(stage + ps * 64 + ((j ^ (ps & 7)) << 3)) = v;
    }
    __syncthreads();

    int lane = t & 63;
    int wave = t >> 6;
    int kh = wave >> 2;
    int wv = wave & 3;
    int sp = wv * 16 + (lane & 15);
    int px = pxbase + sp;
    int p = px & 16383;
    int cg = lane >> 4;
    int c0 = kh * 32 + cg * 8;
    int cch = kh * 4 + cg;              // 16B chunk index within a pixel's 128B row

    const bf16x8* wfv = (const bf16x8*)wf;

    f32x4 acc[4];
#pragma unroll
    for (int m = 0; m < 4; m++) acc[m] = (f32x4){0.f, 0.f, 0.f, 0.f};

#pragma unroll
    for (int k = 0; k < 9; k++) {
        int s = k * 64 + sp;
        u32x4 gc[4];
#pragma unroll
        for (int c = 0; c < 4; c++) {
            int o = tof[c][s];
            int y = o >> 7, x = o & 127;
            int ly = y - ybase, lx = x - xbase;
            bool inw = ((unsigned)ly < 7u) & ((unsigned)lx < 70u);
            int ps = min(max(ly, 0), 6) * 70 + min(max(lx, 0), 69);
            u32x4 v = *(const u32x4*)(stage + ps * 64 + ((cch ^ (ps & 7)) << 3));
            if (!inw) v = *(const u32x4*)(xb + (size_t)o * 64 + c0);   // ~never
            gc[c] = v;
        }
        float w00 = tw[0][s], w01 = tw[1][s], w10 = tw[2][s], w11 = tw[3][s];

        unsigned ow[4];
#pragma unroll
        for (int wd = 0; wd < 4; wd++) {
            float slo = w00 * bflo(gc[0][wd]);
            slo = fmaf(w01, bflo(gc[1][wd]), slo);
            slo = fmaf(w10, bflo(gc[2][wd]), slo);
            slo = fmaf(w11, bflo(gc[3][wd]), slo);
            float shi = w00 * bfhi(gc[0][wd]);
            shi = fmaf(w01, bfhi(gc[1][wd]), shi);
            shi = fmaf(w10, bfhi(gc[2][wd]), shi);
            shi = fmaf(w11, bfhi(gc[3][wd]), shi);
            ow[wd] = (unsigned)f2bf(slo) | ((unsigned)f2bf(shi) << 16);
        }
        u32x4 owv = {ow[0], ow[1], ow[2], ow[3]};
        bf16x8 bF = __builtin_bit_cast(bf16x8, owv);

        bf16x8 aF[4];
#pragma unroll
        for (int m = 0; m < 4; m++)
            aF[m] = wfv[((k * 4 + m) * 2 + kh) * 64 + lane];
#pragma unroll
        for (int m = 0; m < 4; m++)
            acc[m] = __builtin_amdgcn_mfma_f32_16x16x32_bf16(aF[m], bF, acc[m], 0, 0, 0);
    }

    // ---- reduce kh halves (red aliases the now-dead stage) ----
    __syncthreads();
    float* red = (float*)stage;
    if (kh == 1) {
#pragma unroll
        for (int m = 0; m < 4; m++)
#pragma unroll
            for (int j = 0; j < 4; j++)
                red[(m * 4 + j) * 256 + wv * 64 + lane] = acc[m][j];
    }
    __syncthreads();
    if (kh == 0) {
        unsigned short* drow = outn + (size_t)px * 64;
#pragma unroll
        for (int m = 0; m < 4; m++) {
            int ocb = m * 16 + cg * 4;
            unsigned short pk[4];
#pragma unroll
            for (int r = 0; r < 4; r++) {
                int oc = ocb + r;
                float v = acc[m][r] + red[(m * 4 + r) * 256 + wv * 64 + lane] + bias[oc];
                if (EPI == 0) v = (v >= 0.f) ? v : 0.01f * v;
                if (EPI == 1) v += resid[((size_t)b * 64 + oc) * HW + p];
                pk[r] = f2bf(v);
            }
            *(ushort4*)(drow + ocb) = *(ushort4*)pk;
        }
    }
}

extern "C" void kernel_launch(void* const* d_in, const int* in_sizes, int n_in,
                              void* d_out, int out_size, void* d_ws, size_t ws_size,
                              hipStream_t stream)
{
    const float* input  = (const float*)d_in[0];
    const float* offset = (const float*)d_in[1];
    const float* w_off1 = (const float*)d_in[2];
    const float* b_off1 = (const float*)d_in[3];
    const float* w1     = (const float*)d_in[4];
    const float* b1     = (const float*)d_in[5];
    const float* w_off2 = (const float*)d_in[6];
    const float* b_off2 = (const float*)d_in[7];
    const float* w2     = (const float*)d_in[8];
    const float* b2     = (const float*)d_in[9];
    const float* w_last = (const float*)d_in[10];
    const float* b_last = (const float*)d_in[11];
    float* out = (float*)d_out;

    float* ws = (float*)d_ws;
    float* om = ws;                                        // 3,538,944 f
    unsigned short* xn   = (unsigned short*)(om + 3538944);   // 4,194,304 ush
    unsigned short* offn = xn + 4194304;                   // 2,097,152 ush
    unsigned short* x1n  = offn + 2097152;                 // 4,194,304 ush
    unsigned short* x2n  = x1n + 4194304;                  // 4,194,304 ush
    unsigned short* wfo  = x2n + 4194304;                  // 18,432 ush
    unsigned short* wf1  = wfo + 18432;                    // 36,864 ush
    unsigned short* wf2  = wf1 + 36864;                    // 36,864 ush
    unsigned short* wfl  = wf2 + 36864;                    // 36,864 ush
    float* bias54 = (float*)(wfl + 36864);                 // 64 f

    repack_mfma<<<dim3(72),  256, 0, stream>>>(w_off1, w_off2, 27, 54, 32, 1, wfo);
    repack_mfma<<<dim3(144), 256, 0, stream>>>(w1, w1, 64, 64, 64, 2, wf1);
    repack_mfma<<<dim3(144), 256, 0, stream>>>(w2, w2, 64, 64, 64, 2, wf2);
    repack_mfma<<<dim3(144), 256, 0, stream>>>(w_last, w_last, 64, 64, 64, 2, wfl);
    bias_concat_kernel<<<dim3(1), 64, 0, stream>>>(b_off1, b_off2, bias54);

    // 131072 threads = 512 blocks (input 65536 px + offset 65536 px)
    to_nhwc<<<dim3(512), 256, 0, stream>>>(input, offset, xn, offn);

    // offset conv (54 oc) from NHWC offset -> om (NCHW fp32)
    conv_direct<32, 54><<<dim3(1024), 256, 0, stream>>>(offn, wfo, bias54, om);
    // DCN 1: sample xn, leaky -> x1n (NHWC bf16)
    dcn_stage<0><<<dim3(1024), 512, 0, stream>>>(xn, om, 0, wf1, b1, nullptr, x1n);
    // DCN 2: sample x1n, + input residual -> x2n (NHWC bf16)
    dcn_stage<1><<<dim3(1024), 512, 0, stream>>>(x1n, om, 27, wf2, b2, input, x2n);
    // final conv from x2n -> out (NCHW fp32)
    conv_direct2<<<dim3(1024), 512, 0, stream>>>(x2n, wfl, b_last, out);
}

// Round 9
// 104.019 us; speedup vs baseline: 1.4110x; 1.1794x over previous
//
#include <hip/hip_runtime.h>
#include <cmath>

#define HW   16384
#define Wd   128
#define Hd   128
#define NB   4

typedef __attribute__((ext_vector_type(8))) _Float16 h16x8;
typedef __attribute__((ext_vector_type(4))) float f32x4;
typedef __attribute__((ext_vector_type(4))) unsigned int u32x4;

__device__ inline unsigned short f2h(float f) {
    _Float16 h = (_Float16)f;
    return __builtin_bit_cast(unsigned short, h);
}

// ---------- fused prep: weight repacks (fp16 MFMA A-frag layout) + bias + NHWC transposes ----------
// repack dst: [9][4 m][KS][64 lane][8 e]; (k,m,ks,lane,e) <- w[oc][c][k], oc=m*16+(lane&15),
// c=ks*32+(lane>>4)*8+e; src1 for oc<Osplit else src2; zero-pad OOB.
__device__ inline void repack_one(int idx, const float* __restrict__ s1, const float* __restrict__ s2,
                                  int Osplit, int O, int CIN, int KS, unsigned short* __restrict__ dst) {
    int e    = idx & 7;
    int lane = (idx >> 3) & 63;
    int ks   = (idx >> 9) % KS;
    int m    = (idx / (512 * KS)) & 3;
    int k    = idx / (2048 * KS);
    int oc = m * 16 + (lane & 15);
    int c  = ks * 32 + (lane >> 4) * 8 + e;
    float v = 0.f;
    if (oc < O && c < CIN)
        v = (oc < Osplit) ? s1[((size_t)oc * CIN + c) * 9 + k]
                          : s2[((size_t)(oc - Osplit) * CIN + c) * 9 + k];
    dst[idx] = f2h(v);
}

__global__ __launch_bounds__(256) void prep(
    const float* __restrict__ input, const float* __restrict__ offset,
    const float* __restrict__ w_off1, const float* __restrict__ w_off2,
    const float* __restrict__ b_off1, const float* __restrict__ b_off2,
    const float* __restrict__ w1, const float* __restrict__ w2, const float* __restrict__ w_last,
    unsigned short* __restrict__ xn, unsigned short* __restrict__ offn,
    unsigned short* __restrict__ wfo, unsigned short* __restrict__ wf1,
    unsigned short* __restrict__ wf2, unsigned short* __restrict__ wfl,
    float* __restrict__ bias54)
{
    int blk = blockIdx.x;
    if (blk < 512) {
        int t = blk * 256 + threadIdx.x;
        if (t < 65536) {
            int b = t >> 14, p = t & 16383;
            const float* s = input + ((size_t)b * 64) * HW + p;
            unsigned short* d = xn + (size_t)t * 64;
#pragma unroll
            for (int g = 0; g < 8; g++) {
                unsigned short pk[8];
#pragma unroll
                for (int e = 0; e < 8; e++) pk[e] = f2h(s[(size_t)(g * 8 + e) * HW]);
                *(u32x4*)(d + g * 8) = *(u32x4*)pk;
            }
        } else {
            int u = t - 65536;
            int b = u >> 14, p = u & 16383;
            const float* s = offset + ((size_t)b * 32) * HW + p;
            unsigned short* d = offn + (size_t)u * 32;
#pragma unroll
            for (int g = 0; g < 4; g++) {
                unsigned short pk[8];
#pragma unroll
                for (int e = 0; e < 8; e++) pk[e] = f2h(s[(size_t)(g * 8 + e) * HW]);
                *(u32x4*)(d + g * 8) = *(u32x4*)pk;
            }
        }
    } else {
        int u = (blk - 512) * 256 + threadIdx.x;
        if (u < 18432)        repack_one(u, w_off1, w_off2, 27, 54, 32, 1, wfo);
        else if (u < 55296)   repack_one(u - 18432, w1, w1, 64, 64, 64, 2, wf1);
        else if (u < 92160)   repack_one(u - 55296, w2, w2, 64, 64, 64, 2, wf2);
        else if (u < 129024)  repack_one(u - 92160, w_last, w_last, 64, 64, 64, 2, wfl);
        else if (u < 129078) {
            int j = u - 129024;
            bias54[j] = (j < 27) ? b_off1[j] : b_off2[j - 27];
        }
    }
}

// ---------- small conv (CIN=32): 4-wave direct, fp16 MFMA ----------
template<int CIN, int OCT>
__global__ __launch_bounds__(256, 4) void conv_direct(
    const unsigned short* __restrict__ xn, const unsigned short* __restrict__ wf,
    const float* __restrict__ bias, float* __restrict__ out)
{
    constexpr int KS = CIN / 32;
    int lb = ((blockIdx.x & 7) << 7) | (blockIdx.x >> 3);
    int t = threadIdx.x;
    int lane = t & 63, wv = t >> 6;
    int px = lb * 64 + wv * 16 + (lane & 15);
    int b = px >> 14, p = px & 16383;
    int row = p >> 7, col = p & 127;
    int cg = lane >> 4;

    const h16x8* wfv = (const h16x8*)wf;
    f32x4 acc[4];
#pragma unroll
    for (int m = 0; m < 4; m++) acc[m] = (f32x4){0.f, 0.f, 0.f, 0.f};

    auto loadB = [&](int k, h16x8* bq) {
        int hh = row + k / 3 - 1, ww = col + k % 3 - 1;
        bool ok = (hh >= 0) & (hh < Hd) & (ww >= 0) & (ww < Wd);
        size_t base = ((size_t)(b << 14) + hh * Wd + ww) * CIN;
#pragma unroll
        for (int ks = 0; ks < KS; ks++) {
            h16x8 v = (h16x8)0;
            if (ok) v = *(const h16x8*)(xn + base + ks * 32 + cg * 8);
            bq[ks] = v;
        }
    };

    h16x8 bq[KS];
    loadB(0, bq);

#pragma unroll
    for (int k = 0; k < 9; k++) {
        h16x8 aF[4 * KS];
#pragma unroll
        for (int m = 0; m < 4; m++)
#pragma unroll
            for (int ks = 0; ks < KS; ks++)
                aF[m * KS + ks] = wfv[((k * 4 + m) * KS + ks) * 64 + lane];

        h16x8 bn[KS];
        if (k < 8) loadB(k + 1, bn);

#pragma unroll
        for (int ks = 0; ks < KS; ks++)
#pragma unroll
            for (int m = 0; m < 4; m++)
                acc[m] = __builtin_amdgcn_mfma_f32_16x16x32_f16(aF[m * KS + ks], bq[ks], acc[m], 0, 0, 0);

        if (k < 8) {
#pragma unroll
            for (int ks = 0; ks < KS; ks++) bq[ks] = bn[ks];
        }
    }

#pragma unroll
    for (int m = 0; m < 4; m++) {
        int ocb = m * 16 + cg * 4;
#pragma unroll
        for (int r = 0; r < 4; r++) {
            int oc = ocb + r;
            if (OCT == 64 || oc < OCT)
                out[((size_t)b * OCT + oc) * HW + p] = acc[m][r] + bias[oc];
        }
    }
}

// ---------- conv3x3 CIN=64, 8 waves, K-split, fp16 MFMA ----------
__global__ __launch_bounds__(512, 8) void conv_direct2(
    const unsigned short* __restrict__ xn, const unsigned short* __restrict__ wf,
    const float* __restrict__ bias, float* __restrict__ out)
{
    __shared__ float red[16 * 256];
    int lb = ((blockIdx.x & 7) << 7) | (blockIdx.x >> 3);
    int t = threadIdx.x;
    int lane = t & 63;
    int wave = t >> 6;
    int kh = wave >> 2;
    int wv = wave & 3;
    int px = lb * 64 + wv * 16 + (lane & 15);
    int b = px >> 14, p = px & 16383;
    int row = p >> 7, col = p & 127;
    int cg = lane >> 4;
    int c0 = kh * 32 + cg * 8;

    const h16x8* wfv = (const h16x8*)wf;
    f32x4 acc[4];
#pragma unroll
    for (int m = 0; m < 4; m++) acc[m] = (f32x4){0.f, 0.f, 0.f, 0.f};

    auto loadB = [&](int k) -> h16x8 {
        int hh = row + k / 3 - 1, ww = col + k % 3 - 1;
        bool ok = (hh >= 0) & (hh < Hd) & (ww >= 0) & (ww < Wd);
        size_t base = ((size_t)(b << 14) + hh * Wd + ww) * 64;
        h16x8 v = (h16x8)0;
        if (ok) v = *(const h16x8*)(xn + base + c0);
        return v;
    };

    h16x8 bq = loadB(0);
#pragma unroll
    for (int k = 0; k < 9; k++) {
        h16x8 aF[4];
#pragma unroll
        for (int m = 0; m < 4; m++)
            aF[m] = wfv[((k * 4 + m) * 2 + kh) * 64 + lane];
        h16x8 bn;
        if (k < 8) bn = loadB(k + 1);
#pragma unroll
        for (int m = 0; m < 4; m++)
            acc[m] = __builtin_amdgcn_mfma_f32_16x16x32_f16(aF[m], bq, acc[m], 0, 0, 0);
        if (k < 8) bq = bn;
    }

    if (kh == 1) {
#pragma unroll
        for (int m = 0; m < 4; m++)
#pragma unroll
            for (int j = 0; j < 4; j++)
                red[(m * 4 + j) * 256 + wv * 64 + lane] = acc[m][j];
    }
    __syncthreads();
    if (kh == 0) {
#pragma unroll
        for (int m = 0; m < 4; m++) {
            int ocb = m * 16 + cg * 4;
#pragma unroll
            for (int r = 0; r < 4; r++) {
                int oc = ocb + r;
                float v = acc[m][r] + red[(m * 4 + r) * 256 + wv * 64 + lane] + bias[oc];
                out[((size_t)b * 64 + oc) * HW + p] = v;
            }
        }
    }
}

// ---------- DCNv2 sampling helpers ----------
struct Tap { float w00, w01, w10, w11; int o00, o01, o10, o11; };

__device__ inline Tap mkparams(float oy, float ox, float mv, int row, int col, int k) {
    Tap P;
    float mk = 1.f / (1.f + __expf(-mv));
    float ys = (float)(row + k / 3 - 1) + oy;
    float xs = (float)(col + k % 3 - 1) + ox;
    float y0f = floorf(ys), x0f = floorf(xs);
    float fy = ys - y0f, fx = xs - x0f;
    int y0 = (int)y0f, x0 = (int)x0f;
    int y1 = y0 + 1, x1 = x0 + 1;
    bool vy0 = (y0 >= 0) & (y0 < Hd);
    bool vy1 = (y1 >= 0) & (y1 < Hd);
    bool vx0 = (x0 >= 0) & (x0 < Wd);
    bool vx1 = (x1 >= 0) & (x1 < Wd);
    P.w00 = (vy0 && vx0) ? (1.f - fy) * (1.f - fx) * mk : 0.f;
    P.w01 = (vy0 && vx1) ? (1.f - fy) * fx * mk : 0.f;
    P.w10 = (vy1 && vx0) ? fy * (1.f - fx) * mk : 0.f;
    P.w11 = (vy1 && vx1) ? fy * fx * mk : 0.f;
    int iy0 = min(max(y0, 0), Hd - 1) * Wd;
    int iy1 = min(max(y1, 0), Hd - 1) * Wd;
    int ix0 = min(max(x0, 0), Wd - 1);
    int ix1 = min(max(x1, 0), Wd - 1);
    P.o00 = iy0 + ix0; P.o01 = iy0 + ix1; P.o10 = iy1 + ix0; P.o11 = iy1 + ix1;
    return P;
}

// ---------- DCNv2, LDS-staged window, fp16 packed bilinear ----------
// EPI 0: leaky -> outn (NHWC fp16). EPI 1: +resid(NCHW fp32) -> outn (NHWC fp16).
template<int EPI>
__global__ __launch_bounds__(512, 4) void dcn_stage(
    const unsigned short* __restrict__ xn, const float* __restrict__ om, int omOff,
    const unsigned short* __restrict__ wf, const float* __restrict__ bias,
    const float* __restrict__ resid, unsigned short* __restrict__ outn)
{
    __shared__ __align__(16) unsigned short stage[490 * 64];  // 7x70 px-slots x 64ch = 62.7KB
    __shared__ float tw[4][576];
    __shared__ unsigned short tof[4][576];

    int lb = ((blockIdx.x & 7) << 7) | (blockIdx.x >> 3);
    int t = threadIdx.x;
    int pxbase = lb * 64;
    int b = pxbase >> 14;
    int pbase = pxbase & 16383;
    int rowbase = pbase >> 7;
    int colbase = pbase & 127;
    int ybase = rowbase - 3;
    int xbase = colbase - 3;
    const unsigned short* xb = xn + ((size_t)(b << 14)) * 64;

    // phase 1a: tap params
    for (int s = t; s < 576; s += 512) {
        int k = s >> 6, sp = s & 63;
        int p = pbase + sp;
        int row = p >> 7, col = p & 127;
        const float* omb = om + ((size_t)b * 54 + omOff) * HW + p;
        float oy = omb[(size_t)(2 * k) * HW];
        float ox = omb[(size_t)(2 * k + 1) * HW];
        float mv = omb[(size_t)(18 + k) * HW];
        Tap P = mkparams(oy, ox, mv, row, col, k);
        tw[0][s] = P.w00; tw[1][s] = P.w01; tw[2][s] = P.w10; tw[3][s] = P.w11;
        tof[0][s] = (unsigned short)P.o00; tof[1][s] = (unsigned short)P.o01;
        tof[2][s] = (unsigned short)P.o10; tof[3][s] = (unsigned short)P.o11;
    }
    // phase 1b: stage fill, coalesced, chunk-swizzled
    for (int q = t; q < 3920; q += 512) {
        int ps = q >> 3, j = q & 7;
        int ly = ps / 70, lx = ps - ly * 70;
        int y = min(max(ybase + ly, 0), Hd - 1);
        int x = min(max(xbase + lx, 0), Wd - 1);
        u32x4 v = *(const u32x4*)(xb + ((size_t)(y * Wd + x)) * 64 + j * 8);
        *(u32x4*)(stage + ps * 64 + ((j ^ (ps & 7)) << 3)) = v;
    }
    __syncthreads();

    int lane = t & 63;
    int wave = t >> 6;
    int kh = wave >> 2;
    int wv = wave & 3;
    int sp = wv * 16 + (lane & 15);
    int px = pxbase + sp;
    int p = px & 16383;
    int cg = lane >> 4;
    int c0 = kh * 32 + cg * 8;
    int cch = kh * 4 + cg;

    const h16x8* wfv = (const h16x8*)wf;

    f32x4 acc[4];
#pragma unroll
    for (int m = 0; m < 4; m++) acc[m] = (f32x4){0.f, 0.f, 0.f, 0.f};

#pragma unroll
    for (int k = 0; k < 9; k++) {
        int s = k * 64 + sp;
        h16x8 gc[4];
#pragma unroll
        for (int c = 0; c < 4; c++) {
            int o = tof[c][s];
            int y = o >> 7, x = o & 127;
            int ly = y - ybase, lx = x - xbase;
            bool inw = ((unsigned)ly < 7u) & ((unsigned)lx < 70u);
            int ps = min(max(ly, 0), 6) * 70 + min(max(lx, 0), 69);
            h16x8 v = *(const h16x8*)(stage + ps * 64 + ((cch ^ (ps & 7)) << 3));
            if (!inw) v = *(const h16x8*)(xb + (size_t)o * 64 + c0);   // ~never
            gc[c] = v;
        }
        // packed fp16 bilinear combine (v_pk_fma_f16)
        _Float16 h00 = (_Float16)tw[0][s], h01 = (_Float16)tw[1][s];
        _Float16 h10 = (_Float16)tw[2][s], h11 = (_Float16)tw[3][s];
        h16x8 bF = gc[0] * h00;
        bF = gc[1] * h01 + bF;
        bF = gc[2] * h10 + bF;
        bF = gc[3] * h11 + bF;

        h16x8 aF[4];
#pragma unroll
        for (int m = 0; m < 4; m++)
            aF[m] = wfv[((k * 4 + m) * 2 + kh) * 64 + lane];
#pragma unroll
        for (int m = 0; m < 4; m++)
            acc[m] = __builtin_amdgcn_mfma_f32_16x16x32_f16(aF[m], bF, acc[m], 0, 0, 0);
    }

    // reduce kh halves (red aliases dead stage)
    __syncthreads();
    float* red = (float*)stage;
    if (kh == 1) {
#pragma unroll
        for (int m = 0; m < 4; m++)
#pragma unroll
            for (int j = 0; j < 4; j++)
                red[(m * 4 + j) * 256 + wv * 64 + lane] = acc[m][j];
    }
    __syncthreads();
    if (kh == 0) {
        unsigned short* drow = outn + (size_t)px * 64;
#pragma unroll
        for (int m = 0; m < 4; m++) {
            int ocb = m * 16 + cg * 4;
            unsigned short pk[4];
#pragma unroll
            for (int r = 0; r < 4; r++) {
                int oc = ocb + r;
                float v = acc[m][r] + red[(m * 4 + r) * 256 + wv * 64 + lane] + bias[oc];
                if (EPI == 0) v = (v >= 0.f) ? v : 0.01f * v;
                if (EPI == 1) v += resid[((size_t)b * 64 + oc) * HW + p];
                pk[r] = f2h(v);
            }
            *(ushort4*)(drow + ocb) = *(ushort4*)pk;
        }
    }
}

extern "C" void kernel_launch(void* const* d_in, const int* in_sizes, int n_in,
                              void* d_out, int out_size, void* d_ws, size_t ws_size,
                              hipStream_t stream)
{
    const float* input  = (const float*)d_in[0];
    const float* offset = (const float*)d_in[1];
    const float* w_off1 = (const float*)d_in[2];
    const float* b_off1 = (const float*)d_in[3];
    const float* w1     = (const float*)d_in[4];
    const float* b1     = (const float*)d_in[5];
    const float* w_off2 = (const float*)d_in[6];
    const float* b_off2 = (const float*)d_in[7];
    const float* w2     = (const float*)d_in[8];
    const float* b2     = (const float*)d_in[9];
    const float* w_last = (const float*)d_in[10];
    const float* b_last = (const float*)d_in[11];
    float* out = (float*)d_out;

    float* ws = (float*)d_ws;
    float* om = ws;                                        // 3,538,944 f
    unsigned short* xn   = (unsigned short*)(om + 3538944);   // 4,194,304 ush
    unsigned short* offn = xn + 4194304;                   // 2,097,152 ush
    unsigned short* x1n  = offn + 2097152;                 // 4,194,304 ush
    unsigned short* x2n  = x1n + 4194304;                  // 4,194,304 ush
    unsigned short* wfo  = x2n + 4194304;                  // 18,432 ush
    unsigned short* wf1  = wfo + 18432;                    // 36,864 ush
    unsigned short* wf2  = wf1 + 36864;                    // 36,864 ush
    unsigned short* wfl  = wf2 + 36864;                    // 36,864 ush
    float* bias54 = (float*)(wfl + 36864);                 // 64 f

    // single fused prep launch: transposes (blocks 0..511) + repacks/bias (512..1017)
    prep<<<dim3(1018), 256, 0, stream>>>(input, offset, w_off1, w_off2, b_off1, b_off2,
                                         w1, w2, w_last, xn, offn, wfo, wf1, wf2, wfl, bias54);

    conv_direct<32, 54><<<dim3(1024), 256, 0, stream>>>(offn, wfo, bias54, om);
    dcn_stage<0><<<dim3(1024), 512, 0, stream>>>(xn, om, 0, wf1, b1, nullptr, x1n);
    dcn_stage<1><<<dim3(1024), 512, 0, stream>>>(x1n, om, 27, wf2, b2, input, x2n);
    conv_direct2<<<dim3(1024), 512, 0, stream>>>(x2n, wfl, b_last, out);
}

// Round 11
// 98.630 us; speedup vs baseline: 1.4881x; 1.0546x over previous
//
#include <hip/hip_runtime.h>
#include <cmath>

#define HW   16384
#define Wd   128
#define Hd   128
#define NB   4

typedef __attribute__((ext_vector_type(8))) _Float16 h16x8;
typedef __attribute__((ext_vector_type(4))) float f32x4;
typedef __attribute__((ext_vector_type(4))) unsigned int u32x4;

__device__ inline unsigned short f2h(float f) {
    _Float16 h = (_Float16)f;
    return __builtin_bit_cast(unsigned short, h);
}

// ---------- fused prep: weight repacks (fp16 MFMA A-frag layout) + bias + NHWC transposes ----------
__device__ inline void repack_one(int idx, const float* __restrict__ s1, const float* __restrict__ s2,
                                  int Osplit, int O, int CIN, int KS, unsigned short* __restrict__ dst) {
    int e    = idx & 7;
    int lane = (idx >> 3) & 63;
    int ks   = (idx >> 9) % KS;
    int m    = (idx / (512 * KS)) & 3;
    int k    = idx / (2048 * KS);
    int oc = m * 16 + (lane & 15);
    int c  = ks * 32 + (lane >> 4) * 8 + e;
    float v = 0.f;
    if (oc < O && c < CIN)
        v = (oc < Osplit) ? s1[((size_t)oc * CIN + c) * 9 + k]
                          : s2[((size_t)(oc - Osplit) * CIN + c) * 9 + k];
    dst[idx] = f2h(v);
}

__global__ __launch_bounds__(256) void prep(
    const float* __restrict__ input, const float* __restrict__ offset,
    const float* __restrict__ w_off1, const float* __restrict__ w_off2,
    const float* __restrict__ b_off1, const float* __restrict__ b_off2,
    const float* __restrict__ w1, const float* __restrict__ w2, const float* __restrict__ w_last,
    unsigned short* __restrict__ xn, unsigned short* __restrict__ offn,
    unsigned short* __restrict__ wfo, unsigned short* __restrict__ wf1,
    unsigned short* __restrict__ wf2, unsigned short* __restrict__ wfl,
    float* __restrict__ bias54)
{
    int blk = blockIdx.x;
    if (blk < 512) {
        int t = blk * 256 + threadIdx.x;
        if (t < 65536) {
            int b = t >> 14, p = t & 16383;
            const float* s = input + ((size_t)b * 64) * HW + p;
            unsigned short* d = xn + (size_t)t * 64;
#pragma unroll
            for (int g = 0; g < 8; g++) {
                unsigned short pk[8];
#pragma unroll
                for (int e = 0; e < 8; e++) pk[e] = f2h(s[(size_t)(g * 8 + e) * HW]);
                *(u32x4*)(d + g * 8) = *(u32x4*)pk;
            }
        } else {
            int u = t - 65536;
            int b = u >> 14, p = u & 16383;
            const float* s = offset + ((size_t)b * 32) * HW + p;
            unsigned short* d = offn + (size_t)u * 32;
#pragma unroll
            for (int g = 0; g < 4; g++) {
                unsigned short pk[8];
#pragma unroll
                for (int e = 0; e < 8; e++) pk[e] = f2h(s[(size_t)(g * 8 + e) * HW]);
                *(u32x4*)(d + g * 8) = *(u32x4*)pk;
            }
        }
    } else {
        int u = (blk - 512) * 256 + threadIdx.x;
        if (u < 18432)        repack_one(u, w_off1, w_off2, 27, 54, 32, 1, wfo);
        else if (u < 55296)   repack_one(u - 18432, w1, w1, 64, 64, 64, 2, wf1);
        else if (u < 92160)   repack_one(u - 55296, w2, w2, 64, 64, 64, 2, wf2);
        else if (u < 129024)  repack_one(u - 92160, w_last, w_last, 64, 64, 64, 2, wfl);
        else if (u < 129078) {
            int j = u - 129024;
            bias54[j] = (j < 27) ? b_off1[j] : b_off2[j - 27];
        }
    }
}

// ---------- conv3x3 CIN=32 (offset conv), LDS-staged window, 4 waves ----------
__global__ __launch_bounds__(256, 4) void conv_stage32(
    const unsigned short* __restrict__ xn, const unsigned short* __restrict__ wf,
    const float* __restrict__ bias, float* __restrict__ out)
{
    __shared__ __align__(16) unsigned short stage[198 * 32];   // 3x66 px x 32ch
    int lb = ((blockIdx.x & 7) << 7) | (blockIdx.x >> 3);
    int t = threadIdx.x;
    int pxbase = lb * 64;
    int b = pxbase >> 14;
    int pbase = pxbase & 16383;
    int rowbase = pbase >> 7, colbase = pbase & 127;
    const unsigned short* xb = xn + ((size_t)(b << 14)) * 32;

    for (int q = t; q < 792; q += 256) {
        int ps = q >> 2, j = q & 3;
        int ly = ps / 66, lx = ps - ly * 66;
        int y = rowbase - 1 + ly, x = colbase - 1 + lx;
        bool ok = (y >= 0) & (y < Hd) & (x >= 0) & (x < Wd);
        u32x4 v = {0, 0, 0, 0};
        if (ok) v = *(const u32x4*)(xb + ((size_t)(y * Wd + x)) * 32 + j * 8);
        *(u32x4*)(stage + ps * 32 + ((j ^ (ps & 3)) << 3)) = v;
    }
    __syncthreads();

    int lane = t & 63, wv = t >> 6;
    int sp = wv * 16 + (lane & 15);
    int px = pxbase + sp;
    int p = px & 16383;
    int cg = lane >> 4;

    const h16x8* wfv = (const h16x8*)wf;
    f32x4 acc[4];
#pragma unroll
    for (int m = 0; m < 4; m++) acc[m] = (f32x4){0.f, 0.f, 0.f, 0.f};

#pragma unroll
    for (int k = 0; k < 9; k++) {
        int ps = (k / 3) * 66 + sp + (k % 3);
        h16x8 bq = *(const h16x8*)(stage + ps * 32 + ((cg ^ (ps & 3)) << 3));
        h16x8 aF[4];
#pragma unroll
        for (int m = 0; m < 4; m++)
            aF[m] = wfv[(k * 4 + m) * 64 + lane];
#pragma unroll
        for (int m = 0; m < 4; m++)
            acc[m] = __builtin_amdgcn_mfma_f32_16x16x32_f16(aF[m], bq, acc[m], 0, 0, 0);
    }

#pragma unroll
    for (int m = 0; m < 4; m++) {
        int ocb = m * 16 + cg * 4;
#pragma unroll
        for (int r = 0; r < 4; r++) {
            int oc = ocb + r;
            if (oc < 54)
                out[((size_t)b * 54 + oc) * HW + p] = acc[m][r] + bias[oc];
        }
    }
}

// ---------- conv3x3 CIN=64 (final conv), LDS-staged window, 8 waves kh-split ----------
__global__ __launch_bounds__(512, 8) void conv_stage64(
    const unsigned short* __restrict__ xn, const unsigned short* __restrict__ wf,
    const float* __restrict__ bias, float* __restrict__ out)
{
    __shared__ __align__(16) unsigned short stage[198 * 64];   // 3x66 px x 64ch
    int lb = ((blockIdx.x & 7) << 7) | (blockIdx.x >> 3);
    int t = threadIdx.x;
    int pxbase = lb * 64;
    int b = pxbase >> 14;
    int pbase = pxbase & 16383;
    int rowbase = pbase >> 7, colbase = pbase & 127;
    const unsigned short* xb = xn + ((size_t)(b << 14)) * 64;

    for (int q = t; q < 1584; q += 512) {
        int ps = q >> 3, j = q & 7;
        int ly = ps / 66, lx = ps - ly * 66;
        int y = rowbase - 1 + ly, x = colbase - 1 + lx;
        bool ok = (y >= 0) & (y < Hd) & (x >= 0) & (x < Wd);
        u32x4 v = {0, 0, 0, 0};
        if (ok) v = *(const u32x4*)(xb + ((size_t)(y * Wd + x)) * 64 + j * 8);
        *(u32x4*)(stage + ps * 64 + ((j ^ (ps & 7)) << 3)) = v;
    }
    __syncthreads();

    int lane = t & 63;
    int wave = t >> 6;
    int kh = wave >> 2;
    int wv = wave & 3;
    int sp = wv * 16 + (lane & 15);
    int px = pxbase + sp;
    int p = px & 16383;
    int cg = lane >> 4;
    int cch = kh * 4 + cg;

    const h16x8* wfv = (const h16x8*)wf;
    f32x4 acc[4];
#pragma unroll
    for (int m = 0; m < 4; m++) acc[m] = (f32x4){0.f, 0.f, 0.f, 0.f};

#pragma unroll
    for (int k = 0; k < 9; k++) {
        int ps = (k / 3) * 66 + sp + (k % 3);
        h16x8 bq = *(const h16x8*)(stage + ps * 64 + ((cch ^ (ps & 7)) << 3));
        h16x8 aF[4];
#pragma unroll
        for (int m = 0; m < 4; m++)
            aF[m] = wfv[((k * 4 + m) * 2 + kh) * 64 + lane];
#pragma unroll
        for (int m = 0; m < 4; m++)
            acc[m] = __builtin_amdgcn_mfma_f32_16x16x32_f16(aF[m], bq, acc[m], 0, 0, 0);
    }

    __syncthreads();                 // stage reads done; red aliases stage
    float* red = (float*)stage;
    if (kh == 1) {
#pragma unroll
        for (int m = 0; m < 4; m++)
#pragma unroll
            for (int j = 0; j < 4; j++)
                red[(m * 4 + j) * 256 + wv * 64 + lane] = acc[m][j];
    }
    __syncthreads();
    if (kh == 0) {
#pragma unroll
        for (int m = 0; m < 4; m++) {
            int ocb = m * 16 + cg * 4;
#pragma unroll
            for (int r = 0; r < 4; r++) {
                int oc = ocb + r;
                float v = acc[m][r] + red[(m * 4 + r) * 256 + wv * 64 + lane] + bias[oc];
                out[((size_t)b * 64 + oc) * HW + p] = v;
            }
        }
    }
}

// ---------- DCNv2 sampling helpers (R9 passing version, verbatim) ----------
struct Tap { float w00, w01, w10, w11; int o00, o01, o10, o11; };

__device__ inline Tap mkparams(float oy, float ox, float mv, int row, int col, int k) {
    Tap P;
    float mk = 1.f / (1.f + __expf(-mv));
    float ys = (float)(row + k / 3 - 1) + oy;
    float xs = (float)(col + k % 3 - 1) + ox;
    float y0f = floorf(ys), x0f = floorf(xs);
    float fy = ys - y0f, fx = xs - x0f;
    int y0 = (int)y0f, x0 = (int)x0f;
    int y1 = y0 + 1, x1 = x0 + 1;
    bool vy0 = (y0 >= 0) & (y0 < Hd);
    bool vy1 = (y1 >= 0) & (y1 < Hd);
    bool vx0 = (x0 >= 0) & (x0 < Wd);
    bool vx1 = (x1 >= 0) & (x1 < Wd);
    P.w00 = (vy0 && vx0) ? (1.f - fy) * (1.f - fx) * mk : 0.f;
    P.w01 = (vy0 && vx1) ? (1.f - fy) * fx * mk : 0.f;
    P.w10 = (vy1 && vx0) ? fy * (1.f - fx) * mk : 0.f;
    P.w11 = (vy1 && vx1) ? fy * fx * mk : 0.f;
    int iy0 = min(max(y0, 0), Hd - 1) * Wd;
    int iy1 = min(max(y1, 0), Hd - 1) * Wd;
    int ix0 = min(max(x0, 0), Wd - 1);
    int ix1 = min(max(x1, 0), Wd - 1);
    P.o00 = iy0 + ix0; P.o01 = iy0 + ix1; P.o10 = iy1 + ix0; P.o11 = iy1 + ix1;
    return P;
}

// ---------- DCNv2, LDS-staged window (R9 passing version, verbatim) ----------
// EPI 0: leaky -> outn (NHWC fp16). EPI 1: +resid(NCHW fp32) -> outn (NHWC fp16).
template<int EPI>
__global__ __launch_bounds__(512, 4) void dcn_stage(
    const unsigned short* __restrict__ xn, const float* __restrict__ om, int omOff,
    const unsigned short* __restrict__ wf, const float* __restrict__ bias,
    const float* __restrict__ resid, unsigned short* __restrict__ outn)
{
    __shared__ __align__(16) unsigned short stage[490 * 64];  // 7x70 px x 64ch = 62.7KB
    __shared__ float tw[4][576];
    __shared__ unsigned short tof[4][576];

    int lb = ((blockIdx.x & 7) << 7) | (blockIdx.x >> 3);
    int t = threadIdx.x;
    int pxbase = lb * 64;
    int b = pxbase >> 14;
    int pbase = pxbase & 16383;
    int rowbase = pbase >> 7;
    int colbase = pbase & 127;
    int ybase = rowbase - 3;
    int xbase = colbase - 3;
    const unsigned short* xb = xn + ((size_t)(b << 14)) * 64;

    // phase 1a: tap params
    for (int s = t; s < 576; s += 512) {
        int k = s >> 6, sp = s & 63;
        int p = pbase + sp;
        int row = p >> 7, col = p & 127;
        const float* omb = om + ((size_t)b * 54 + omOff) * HW + p;
        float oy = omb[(size_t)(2 * k) * HW];
        float ox = omb[(size_t)(2 * k + 1) * HW];
        float mv = omb[(size_t)(18 + k) * HW];
        Tap P = mkparams(oy, ox, mv, row, col, k);
        tw[0][s] = P.w00; tw[1][s] = P.w01; tw[2][s] = P.w10; tw[3][s] = P.w11;
        tof[0][s] = (unsigned short)P.o00; tof[1][s] = (unsigned short)P.o01;
        tof[2][s] = (unsigned short)P.o10; tof[3][s] = (unsigned short)P.o11;
    }
    // phase 1b: stage fill, coalesced, chunk-swizzled
    for (int q = t; q < 3920; q += 512) {
        int ps = q >> 3, j = q & 7;
        int ly = ps / 70, lx = ps - ly * 70;
        int y = min(max(ybase + ly, 0), Hd - 1);
        int x = min(max(xbase + lx, 0), Wd - 1);
        u32x4 v = *(const u32x4*)(xb + ((size_t)(y * Wd + x)) * 64 + j * 8);
        *(u32x4*)(stage + ps * 64 + ((j ^ (ps & 7)) << 3)) = v;
    }
    __syncthreads();

    int lane = t & 63;
    int wave = t >> 6;
    int kh = wave >> 2;
    int wv = wave & 3;
    int sp = wv * 16 + (lane & 15);
    int px = pxbase + sp;
    int p = px & 16383;
    int cg = lane >> 4;
    int c0 = kh * 32 + cg * 8;
    int cch = kh * 4 + cg;

    const h16x8* wfv = (const h16x8*)wf;

    f32x4 acc[4];
#pragma unroll
    for (int m = 0; m < 4; m++) acc[m] = (f32x4){0.f, 0.f, 0.f, 0.f};

#pragma unroll
    for (int k = 0; k < 9; k++) {
        int s = k * 64 + sp;
        h16x8 gc[4];
#pragma unroll
        for (int c = 0; c < 4; c++) {
            int o = tof[c][s];
            int y = o >> 7, x = o & 127;
            int ly = y - ybase, lx = x - xbase;
            bool inw = ((unsigned)ly < 7u) & ((unsigned)lx < 70u);
            int ps = min(max(ly, 0), 6) * 70 + min(max(lx, 0), 69);
            h16x8 v = *(const h16x8*)(stage + ps * 64 + ((cch ^ (ps & 7)) << 3));
            if (!inw) v = *(const h16x8*)(xb + (size_t)o * 64 + c0);   // ~never
            gc[c] = v;
        }
        _Float16 h00 = (_Float16)tw[0][s];
        _Float16 h01 = (_Float16)tw[1][s];
        _Float16 h10 = (_Float16)tw[2][s];
        _Float16 h11 = (_Float16)tw[3][s];
        h16x8 bF = gc[0] * h00;
        bF = gc[1] * h01 + bF;
        bF = gc[2] * h10 + bF;
        bF = gc[3] * h11 + bF;

        h16x8 aF[4];
#pragma unroll
        for (int m = 0; m < 4; m++)
            aF[m] = wfv[((k * 4 + m) * 2 + kh) * 64 + lane];
#pragma unroll
        for (int m = 0; m < 4; m++)
            acc[m] = __builtin_amdgcn_mfma_f32_16x16x32_f16(aF[m], bF, acc[m], 0, 0, 0);
    }

    __syncthreads();
    float* red = (float*)stage;
    if (kh == 1) {
#pragma unroll
        for (int m = 0; m < 4; m++)
#pragma unroll
            for (int j = 0; j < 4; j++)
                red[(m * 4 + j) * 256 + wv * 64 + lane] = acc[m][j];
    }
    __syncthreads();
    if (kh == 0) {
        unsigned short* drow = outn + (size_t)px * 64;
#pragma unroll
        for (int m = 0; m < 4; m++) {
            int ocb = m * 16 + cg * 4;
            unsigned short pk[4];
#pragma unroll
            for (int r = 0; r < 4; r++) {
                int oc = ocb + r;
                float v = acc[m][r] + red[(m * 4 + r) * 256 + wv * 64 + lane] + bias[oc];
                if (EPI == 0) v = (v >= 0.f) ? v : 0.01f * v;
                if (EPI == 1) v += resid[((size_t)b * 64 + oc) * HW + p];
                pk[r] = f2h(v);
            }
            *(ushort4*)(drow + ocb) = *(ushort4*)pk;
        }
    }
}

extern "C" void kernel_launch(void* const* d_in, const int* in_sizes, int n_in,
                              void* d_out, int out_size, void* d_ws, size_t ws_size,
                              hipStream_t stream)
{
    const float* input  = (const float*)d_in[0];
    const float* offset = (const float*)d_in[1];
    const float* w_off1 = (const float*)d_in[2];
    const float* b_off1 = (const float*)d_in[3];
    const float* w1     = (const float*)d_in[4];
    const float* b1     = (const float*)d_in[5];
    const float* w_off2 = (const float*)d_in[6];
    const float* b_off2 = (const float*)d_in[7];
    const float* w2     = (const float*)d_in[8];
    const float* b2     = (const float*)d_in[9];
    const float* w_last = (const float*)d_in[10];
    const float* b_last = (const float*)d_in[11];
    float* out = (float*)d_out;

    float* ws = (float*)d_ws;
    float* om = ws;                                        // 3,538,944 f
    unsigned short* xn   = (unsigned short*)(om + 3538944);   // 4,194,304 ush
    unsigned short* offn = xn + 4194304;                   // 2,097,152 ush
    unsigned short* x1n  = offn + 2097152;                 // 4,194,304 ush
    unsigned short* x2n  = x1n + 4194304;                  // 4,194,304 ush
    unsigned short* wfo  = x2n + 4194304;                  // 18,432 ush
    unsigned short* wf1  = wfo + 18432;                    // 36,864 ush
    unsigned short* wf2  = wf1 + 36864;                    // 36,864 ush
    unsigned short* wfl  = wf2 + 36864;                    // 36,864 ush
    float* bias54 = (float*)(wfl + 36864);                 // 64 f

    prep<<<dim3(1018), 256, 0, stream>>>(input, offset, w_off1, w_off2, b_off1, b_off2,
                                         w1, w2, w_last, xn, offn, wfo, wf1, wf2, wfl, bias54);

    conv_stage32<<<dim3(1024), 256, 0, stream>>>(offn, wfo, bias54, om);
    dcn_stage<0><<<dim3(1024), 512, 0, stream>>>(xn, om, 0, wf1, b1, nullptr, x1n);
    dcn_stage<1><<<dim3(1024), 512, 0, stream>>>(x1n, om, 27, wf2, b2, input, x2n);
    conv_stage64<<<dim3(1024), 512, 0, stream>>>(x2n, wfl, b_last, out);
}

// Round 13
// 97.063 us; speedup vs baseline: 1.5121x; 1.0161x over previous
//
#include <hip/hip_runtime.h>
#include <cmath>

#define HW   16384
#define Wd   128
#define Hd   128
#define NB   4

typedef __attribute__((ext_vector_type(8))) _Float16 h16x8;
typedef __attribute__((ext_vector_type(4))) float f32x4;
typedef __attribute__((ext_vector_type(4))) unsigned int u32x4;

__device__ inline unsigned short f2h(float f) {
    _Float16 h = (_Float16)f;
    return __builtin_bit_cast(unsigned short, h);
}
__device__ inline float h2f(unsigned short u) {
    return (float)__builtin_bit_cast(_Float16, u);
}

// ---------- fused prep: weight repacks (fp16 MFMA A-frag layout) + bias + NHWC transposes ----------
__device__ inline void repack_one(int idx, const float* __restrict__ s1, const float* __restrict__ s2,
                                  int Osplit, int O, int CIN, int KS, unsigned short* __restrict__ dst) {
    int e    = idx & 7;
    int lane = (idx >> 3) & 63;
    int ks   = (idx >> 9) % KS;
    int m    = (idx / (512 * KS)) & 3;
    int k    = idx / (2048 * KS);
    int oc = m * 16 + (lane & 15);
    int c  = ks * 32 + (lane >> 4) * 8 + e;
    float v = 0.f;
    if (oc < O && c < CIN)
        v = (oc < Osplit) ? s1[((size_t)oc * CIN + c) * 9 + k]
                          : s2[((size_t)(oc - Osplit) * CIN + c) * 9 + k];
    dst[idx] = f2h(v);
}

__global__ __launch_bounds__(256) void prep(
    const float* __restrict__ input, const float* __restrict__ offset,
    const float* __restrict__ w_off1, const float* __restrict__ w_off2,
    const float* __restrict__ b_off1, const float* __restrict__ b_off2,
    const float* __restrict__ w1, const float* __restrict__ w2, const float* __restrict__ w_last,
    unsigned short* __restrict__ xn, unsigned short* __restrict__ offn,
    unsigned short* __restrict__ wfo, unsigned short* __restrict__ wf1,
    unsigned short* __restrict__ wf2, unsigned short* __restrict__ wfl,
    float* __restrict__ bias54)
{
    int blk = blockIdx.x;
    if (blk < 512) {
        int t = blk * 256 + threadIdx.x;
        if (t < 65536) {
            int b = t >> 14, p = t & 16383;
            const float* s = input + ((size_t)b * 64) * HW + p;
            unsigned short* d = xn + (size_t)t * 64;
#pragma unroll
            for (int g = 0; g < 8; g++) {
                unsigned short pk[8];
#pragma unroll
                for (int e = 0; e < 8; e++) pk[e] = f2h(s[(size_t)(g * 8 + e) * HW]);
                *(u32x4*)(d + g * 8) = *(u32x4*)pk;
            }
        } else {
            int u = t - 65536;
            int b = u >> 14, p = u & 16383;
            const float* s = offset + ((size_t)b * 32) * HW + p;
            unsigned short* d = offn + (size_t)u * 32;
#pragma unroll
            for (int g = 0; g < 4; g++) {
                unsigned short pk[8];
#pragma unroll
                for (int e = 0; e < 8; e++) pk[e] = f2h(s[(size_t)(g * 8 + e) * HW]);
                *(u32x4*)(d + g * 8) = *(u32x4*)pk;
            }
        }
    } else {
        int u = (blk - 512) * 256 + threadIdx.x;
        if (u < 18432)        repack_one(u, w_off1, w_off2, 27, 54, 32, 1, wfo);
        else if (u < 55296)   repack_one(u - 18432, w1, w1, 64, 64, 64, 2, wf1);
        else if (u < 92160)   repack_one(u - 55296, w2, w2, 64, 64, 64, 2, wf2);
        else if (u < 129024)  repack_one(u - 92160, w_last, w_last, 64, 64, 64, 2, wfl);
        else if (u < 129078) {
            int j = u - 129024;
            bias54[j] = (j < 27) ? b_off1[j] : b_off2[j - 27];
        }
    }
}

// ---------- conv3x3 CIN=32 (offset conv), LDS-staged window, 4 waves; om out fp16 ----------
__global__ __launch_bounds__(256, 4) void conv_stage32(
    const unsigned short* __restrict__ xn, const unsigned short* __restrict__ wf,
    const float* __restrict__ bias, unsigned short* __restrict__ out)
{
    __shared__ __align__(16) unsigned short stage[198 * 32];   // 3x66 px x 32ch
    int lb = ((blockIdx.x & 7) << 7) | (blockIdx.x >> 3);
    int t = threadIdx.x;
    int pxbase = lb * 64;
    int b = pxbase >> 14;
    int pbase = pxbase & 16383;
    int rowbase = pbase >> 7, colbase = pbase & 127;
    const unsigned short* xb = xn + ((size_t)(b << 14)) * 32;

    for (int q = t; q < 792; q += 256) {
        int ps = q >> 2, j = q & 3;
        int ly = ps / 66, lx = ps - ly * 66;
        int y = rowbase - 1 + ly, x = colbase - 1 + lx;
        bool ok = (y >= 0) & (y < Hd) & (x >= 0) & (x < Wd);
        u32x4 v = {0, 0, 0, 0};
        if (ok) v = *(const u32x4*)(xb + ((size_t)(y * Wd + x)) * 32 + j * 8);
        *(u32x4*)(stage + ps * 32 + ((j ^ (ps & 3)) << 3)) = v;
    }
    __syncthreads();

    int lane = t & 63, wv = t >> 6;
    int sp = wv * 16 + (lane & 15);
    int px = pxbase + sp;
    int p = px & 16383;
    int cg = lane >> 4;

    const h16x8* wfv = (const h16x8*)wf;
    f32x4 acc[4];
#pragma unroll
    for (int m = 0; m < 4; m++) acc[m] = (f32x4){0.f, 0.f, 0.f, 0.f};

#pragma unroll
    for (int k = 0; k < 9; k++) {
        int ps = (k / 3) * 66 + sp + (k % 3);
        h16x8 bq = *(const h16x8*)(stage + ps * 32 + ((cg ^ (ps & 3)) << 3));
        h16x8 aF[4];
#pragma unroll
        for (int m = 0; m < 4; m++)
            aF[m] = wfv[(k * 4 + m) * 64 + lane];
#pragma unroll
        for (int m = 0; m < 4; m++)
            acc[m] = __builtin_amdgcn_mfma_f32_16x16x32_f16(aF[m], bq, acc[m], 0, 0, 0);
    }

#pragma unroll
    for (int m = 0; m < 4; m++) {
        int ocb = m * 16 + cg * 4;
#pragma unroll
        for (int r = 0; r < 4; r++) {
            int oc = ocb + r;
            if (oc < 54)
                out[((size_t)b * 54 + oc) * HW + p] = f2h(acc[m][r] + bias[oc]);
        }
    }
}

// ---------- conv3x3 CIN=64 (final conv), LDS-staged window, 8 waves kh-split ----------
__global__ __launch_bounds__(512, 8) void conv_stage64(
    const unsigned short* __restrict__ xn, const unsigned short* __restrict__ wf,
    const float* __restrict__ bias, float* __restrict__ out)
{
    __shared__ __align__(16) unsigned short stage[198 * 64];   // 3x66 px x 64ch
    int lb = ((blockIdx.x & 7) << 7) | (blockIdx.x >> 3);
    int t = threadIdx.x;
    int pxbase = lb * 64;
    int b = pxbase >> 14;
    int pbase = pxbase & 16383;
    int rowbase = pbase >> 7, colbase = pbase & 127;
    const unsigned short* xb = xn + ((size_t)(b << 14)) * 64;

    for (int q = t; q < 1584; q += 512) {
        int ps = q >> 3, j = q & 7;
        int ly = ps / 66, lx = ps - ly * 66;
        int y = rowbase - 1 + ly, x = colbase - 1 + lx;
        bool ok = (y >= 0) & (y < Hd) & (x >= 0) & (x < Wd);
        u32x4 v = {0, 0, 0, 0};
        if (ok) v = *(const u32x4*)(xb + ((size_t)(y * Wd + x)) * 64 + j * 8);
        *(u32x4*)(stage + ps * 64 + ((j ^ (ps & 7)) << 3)) = v;
    }
    __syncthreads();

    int lane = t & 63;
    int wave = t >> 6;
    int kh = wave >> 2;
    int wv = wave & 3;
    int sp = wv * 16 + (lane & 15);
    int px = pxbase + sp;
    int p = px & 16383;
    int cg = lane >> 4;
    int cch = kh * 4 + cg;

    const h16x8* wfv = (const h16x8*)wf;
    f32x4 acc[4];
#pragma unroll
    for (int m = 0; m < 4; m++) acc[m] = (f32x4){0.f, 0.f, 0.f, 0.f};

#pragma unroll
    for (int k = 0; k < 9; k++) {
        int ps = (k / 3) * 66 + sp + (k % 3);
        h16x8 bq = *(const h16x8*)(stage + ps * 64 + ((cch ^ (ps & 7)) << 3));
        h16x8 aF[4];
#pragma unroll
        for (int m = 0; m < 4; m++)
            aF[m] = wfv[((k * 4 + m) * 2 + kh) * 64 + lane];
#pragma unroll
        for (int m = 0; m < 4; m++)
            acc[m] = __builtin_amdgcn_mfma_f32_16x16x32_f16(aF[m], bq, acc[m], 0, 0, 0);
    }

    __syncthreads();                 // stage reads done; red aliases stage
    float* red = (float*)stage;
    if (kh == 1) {
#pragma unroll
        for (int m = 0; m < 4; m++)
#pragma unroll
            for (int j = 0; j < 4; j++)
                red[(m * 4 + j) * 256 + wv * 64 + lane] = acc[m][j];
    }
    __syncthreads();
    if (kh == 0) {
#pragma unroll
        for (int m = 0; m < 4; m++) {
            int ocb = m * 16 + cg * 4;
#pragma unroll
            for (int r = 0; r < 4; r++) {
                int oc = ocb + r;
                float v = acc[m][r] + red[(m * 4 + r) * 256 + wv * 64 + lane] + bias[oc];
                out[((size_t)b * 64 + oc) * HW + p] = v;
            }
        }
    }
}

// ---------- DCNv2 sampling helpers ----------
struct Tap { float w00, w01, w10, w11; int o00, o01, o10, o11; };

__device__ inline Tap mkparams(float oy, float ox, float mv, int row, int col, int k) {
    Tap P;
    float mk = 1.f / (1.f + __expf(-mv));
    float ys = (float)(row + k / 3 - 1) + oy;
    float xs = (float)(col + k % 3 - 1) + ox;
    float y0f = floorf(ys), x0f = floorf(xs);
    float fy = ys - y0f, fx = xs - x0f;
    int y0 = (int)y0f, x0 = (int)x0f;
    int y1 = y0 + 1, x1 = x0 + 1;
    bool vy0 = (y0 >= 0) & (y0 < Hd);
    bool vy1 = (y1 >= 0) & (y1 < Hd);
    bool vx0 = (x0 >= 0) & (x0 < Wd);
    bool vx1 = (x1 >= 0) & (x1 < Wd);
    P.w00 = (vy0 && vx0) ? (1.f - fy) * (1.f - fx) * mk : 0.f;
    P.w01 = (vy0 && vx1) ? (1.f - fy) * fx * mk : 0.f;
    P.w10 = (vy1 && vx0) ? fy * (1.f - fx) * mk : 0.f;
    P.w11 = (vy1 && vx1) ? fy * fx * mk : 0.f;
    int iy0 = min(max(y0, 0), Hd - 1) * Wd;
    int iy1 = min(max(y1, 0), Hd - 1) * Wd;
    int ix0 = min(max(x0, 0), Wd - 1);
    int ix1 = min(max(x1, 0), Wd - 1);
    P.o00 = iy0 + ix0; P.o01 = iy0 + ix1; P.o10 = iy1 + ix0; P.o11 = iy1 + ix1;
    return P;
}

// ---------- DCNv2, LDS-staged window (R11 structure; scalar tap tables; fp16 om) ----------
// EPI 0: leaky -> outn (NHWC fp16). EPI 1: +resid(NCHW fp32) -> outn (NHWC fp16).
template<int EPI>
__global__ __launch_bounds__(512, 4) void dcn_stage(
    const unsigned short* __restrict__ xn, const unsigned short* __restrict__ omh, int omOff,
    const unsigned short* __restrict__ wf, const float* __restrict__ bias,
    const float* __restrict__ resid, unsigned short* __restrict__ outn)
{
    __shared__ __align__(16) unsigned short stage[490 * 64];  // 7x70 px x 64ch = 62.7KB
    __shared__ float tw[4][576];
    __shared__ unsigned short tof[4][576];

    int lb = ((blockIdx.x & 7) << 7) | (blockIdx.x >> 3);
    int t = threadIdx.x;
    int pxbase = lb * 64;
    int b = pxbase >> 14;
    int pbase = pxbase & 16383;
    int rowbase = pbase >> 7;
    int colbase = pbase & 127;
    int ybase = rowbase - 3;
    int xbase = colbase - 3;
    const unsigned short* xb = xn + ((size_t)(b << 14)) * 64;

    // phase 1a: tap params (fp16 om input)
    for (int s = t; s < 576; s += 512) {
        int k = s >> 6, sp = s & 63;
        int p = pbase + sp;
        int row = p >> 7, col = p & 127;
        const unsigned short* omb = omh + ((size_t)b * 54 + omOff) * HW + p;
        float oy = h2f(omb[(size_t)(2 * k) * HW]);
        float ox = h2f(omb[(size_t)(2 * k + 1) * HW]);
        float mv = h2f(omb[(size_t)(18 + k) * HW]);
        Tap P = mkparams(oy, ox, mv, row, col, k);
        tw[0][s] = P.w00; tw[1][s] = P.w01; tw[2][s] = P.w10; tw[3][s] = P.w11;
        tof[0][s] = (unsigned short)P.o00; tof[1][s] = (unsigned short)P.o01;
        tof[2][s] = (unsigned short)P.o10; tof[3][s] = (unsigned short)P.o11;
    }
    // phase 1b: stage fill, coalesced, chunk-swizzled
    for (int q = t; q < 3920; q += 512) {
        int ps = q >> 3, j = q & 7;
        int ly = ps / 70, lx = ps - ly * 70;
        int y = min(max(ybase + ly, 0), Hd - 1);
        int x = min(max(xbase + lx, 0), Wd - 1);
        u32x4 v = *(const u32x4*)(xb + ((size_t)(y * Wd + x)) * 64 + j * 8);
        *(u32x4*)(stage + ps * 64 + ((j ^ (ps & 7)) << 3)) = v;
    }
    __syncthreads();

    int lane = t & 63;
    int wave = t >> 6;
    int kh = wave >> 2;
    int wv = wave & 3;
    int sp = wv * 16 + (lane & 15);
    int px = pxbase + sp;
    int p = px & 16383;
    int cg = lane >> 4;
    int c0 = kh * 32 + cg * 8;
    int cch = kh * 4 + cg;

    const h16x8* wfv = (const h16x8*)wf;

    f32x4 acc[4];
#pragma unroll
    for (int m = 0; m < 4; m++) acc[m] = (f32x4){0.f, 0.f, 0.f, 0.f};

#pragma unroll
    for (int k = 0; k < 9; k++) {
        int s = k * 64 + sp;
        h16x8 gc[4];
#pragma unroll
        for (int c = 0; c < 4; c++) {
            int o = tof[c][s];
            int y = o >> 7, x = o & 127;
            int ly = y - ybase, lx = x - xbase;
            bool inw = ((unsigned)ly < 7u) & ((unsigned)lx < 70u);
            int ps = min(max(ly, 0), 6) * 70 + min(max(lx, 0), 69);
            h16x8 v = *(const h16x8*)(stage + ps * 64 + ((cch ^ (ps & 7)) << 3));
            if (!inw) v = *(const h16x8*)(xb + (size_t)o * 64 + c0);   // ~never
            gc[c] = v;
        }
        _Float16 h00 = (_Float16)tw[0][s];
        _Float16 h01 = (_Float16)tw[1][s];
        _Float16 h10 = (_Float16)tw[2][s];
        _Float16 h11 = (_Float16)tw[3][s];
        h16x8 bF = gc[0] * h00;
        bF = gc[1] * h01 + bF;
        bF = gc[2] * h10 + bF;
        bF = gc[3] * h11 + bF;

        h16x8 aF[4];
#pragma unroll
        for (int m = 0; m < 4; m++)
            aF[m] = wfv[((k * 4 + m) * 2 + kh) * 64 + lane];
#pragma unroll
        for (int m = 0; m < 4; m++)
            acc[m] = __builtin_amdgcn_mfma_f32_16x16x32_f16(aF[m], bF, acc[m], 0, 0, 0);
    }

    __syncthreads();
    float* red = (float*)stage;
    if (kh == 1) {
#pragma unroll
        for (int m = 0; m < 4; m++)
#pragma unroll
            for (int j = 0; j < 4; j++)
                red[(m * 4 + j) * 256 + wv * 64 + lane] = acc[m][j];
    }
    __syncthreads();
    if (kh == 0) {
        unsigned short* drow = outn + (size_t)px * 64;
#pragma unroll
        for (int m = 0; m < 4; m++) {
            int ocb = m * 16 + cg * 4;
            unsigned short pk[4];
#pragma unroll
            for (int r = 0; r < 4; r++) {
                int oc = ocb + r;
                float v = acc[m][r] + red[(m * 4 + r) * 256 + wv * 64 + lane] + bias[oc];
                if (EPI == 0) v = (v >= 0.f) ? v : 0.01f * v;
                if (EPI == 1) v += resid[((size_t)b * 64 + oc) * HW + p];
                pk[r] = f2h(v);
            }
            *(ushort4*)(drow + ocb) = *(ushort4*)pk;
        }
    }
}

extern "C" void kernel_launch(void* const* d_in, const int* in_sizes, int n_in,
                              void* d_out, int out_size, void* d_ws, size_t ws_size,
                              hipStream_t stream)
{
    const float* input  = (const float*)d_in[0];
    const float* offset = (const float*)d_in[1];
    const float* w_off1 = (const float*)d_in[2];
    const float* b_off1 = (const float*)d_in[3];
    const float* w1     = (const float*)d_in[4];
    const float* b1     = (const float*)d_in[5];
    const float* w_off2 = (const float*)d_in[6];
    const float* b_off2 = (const float*)d_in[7];
    const float* w2     = (const float*)d_in[8];
    const float* b2     = (const float*)d_in[9];
    const float* w_last = (const float*)d_in[10];
    const float* b_last = (const float*)d_in[11];
    float* out = (float*)d_out;

    float* ws = (float*)d_ws;
    unsigned short* omh = (unsigned short*)ws;             // fp16 om (region sized as before)
    unsigned short* xn   = (unsigned short*)(ws + 3538944);   // 4,194,304 ush
    unsigned short* offn = xn + 4194304;                   // 2,097,152 ush
    unsigned short* x1n  = offn + 2097152;                 // 4,194,304 ush
    unsigned short* x2n  = x1n + 4194304;                  // 4,194,304 ush
    unsigned short* wfo  = x2n + 4194304;                  // 18,432 ush
    unsigned short* wf1  = wfo + 18432;                    // 36,864 ush
    unsigned short* wf2  = wf1 + 36864;                    // 36,864 ush
    unsigned short* wfl  = wf2 + 36864;                    // 36,864 ush
    float* bias54 = (float*)(wfl + 36864);                 // 64 f

    prep<<<dim3(1018), 256, 0, stream>>>(input, offset, w_off1, w_off2, b_off1, b_off2,
                                         w1, w2, w_last, xn, offn, wfo, wf1, wf2, wfl, bias54);

    conv_stage32<<<dim3(1024), 256, 0, stream>>>(offn, wfo, bias54, omh);
    dcn_stage<0><<<dim3(1024), 512, 0, stream>>>(xn, omh, 0, wf1, b1, nullptr, x1n);
    dcn_stage<1><<<dim3(1024), 512, 0, stream>>>(x1n, omh, 27, wf2, b2, input, x2n);
    conv_stage64<<<dim3(1024), 512, 0, stream>>>(x2n, wfl, b_last, out);
}

// Round 14
// 81.151 us; speedup vs baseline: 1.8086x; 1.1961x over previous
//
#include <hip/hip_runtime.h>
#include <cmath>

#define HW   16384
#define Wd   128
#define Hd   128
#define NB   4

typedef __attribute__((ext_vector_type(8))) _Float16 h16x8;
typedef __attribute__((ext_vector_type(4))) float f32x4;
typedef __attribute__((ext_vector_type(4))) unsigned int u32x4;

__device__ inline unsigned short f2h(float f) {
    _Float16 h = (_Float16)f;
    return __builtin_bit_cast(unsigned short, h);
}
__device__ inline float h2f(unsigned short u) {
    return (float)__builtin_bit_cast(_Float16, u);
}
__device__ inline _Float16 u2h(unsigned short u) {
    return __builtin_bit_cast(_Float16, u);
}

// ---------- fused prep: weight repacks (fp16 MFMA A-frag layout) + bias + NHWC transposes ----------
__device__ inline void repack_one(int idx, const float* __restrict__ s1, const float* __restrict__ s2,
                                  int Osplit, int O, int CIN, int KS, unsigned short* __restrict__ dst) {
    int e    = idx & 7;
    int lane = (idx >> 3) & 63;
    int ks   = (idx >> 9) % KS;
    int m    = (idx / (512 * KS)) & 3;
    int k    = idx / (2048 * KS);
    int oc = m * 16 + (lane & 15);
    int c  = ks * 32 + (lane >> 4) * 8 + e;
    float v = 0.f;
    if (oc < O && c < CIN)
        v = (oc < Osplit) ? s1[((size_t)oc * CIN + c) * 9 + k]
                          : s2[((size_t)(oc - Osplit) * CIN + c) * 9 + k];
    dst[idx] = f2h(v);
}

__global__ __launch_bounds__(256) void prep(
    const float* __restrict__ input, const float* __restrict__ offset,
    const float* __restrict__ w_off1, const float* __restrict__ w_off2,
    const float* __restrict__ b_off1, const float* __restrict__ b_off2,
    const float* __restrict__ w1, const float* __restrict__ w2, const float* __restrict__ w_last,
    unsigned short* __restrict__ xn, unsigned short* __restrict__ offn,
    unsigned short* __restrict__ wfo, unsigned short* __restrict__ wf1,
    unsigned short* __restrict__ wf2, unsigned short* __restrict__ wfl,
    float* __restrict__ bias54)
{
    int blk = blockIdx.x;
    if (blk < 512) {
        int t = blk * 256 + threadIdx.x;
        if (t < 65536) {
            int b = t >> 14, p = t & 16383;
            const float* s = input + ((size_t)b * 64) * HW + p;
            unsigned short* d = xn + (size_t)t * 64;
#pragma unroll
            for (int g = 0; g < 8; g++) {
                unsigned short pk[8];
#pragma unroll
                for (int e = 0; e < 8; e++) pk[e] = f2h(s[(size_t)(g * 8 + e) * HW]);
                *(u32x4*)(d + g * 8) = *(u32x4*)pk;
            }
        } else {
            int u = t - 65536;
            int b = u >> 14, p = u & 16383;
            const float* s = offset + ((size_t)b * 32) * HW + p;
            unsigned short* d = offn + (size_t)u * 32;
#pragma unroll
            for (int g = 0; g < 4; g++) {
                unsigned short pk[8];
#pragma unroll
                for (int e = 0; e < 8; e++) pk[e] = f2h(s[(size_t)(g * 8 + e) * HW]);
                *(u32x4*)(d + g * 8) = *(u32x4*)pk;
            }
        }
    } else {
        int u = (blk - 512) * 256 + threadIdx.x;
        if (u < 18432)        repack_one(u, w_off1, w_off2, 27, 54, 32, 1, wfo);
        else if (u < 55296)   repack_one(u - 18432, w1, w1, 64, 64, 64, 2, wf1);
        else if (u < 92160)   repack_one(u - 55296, w2, w2, 64, 64, 64, 2, wf2);
        else if (u < 129024)  repack_one(u - 92160, w_last, w_last, 64, 64, 64, 2, wfl);
        else if (u < 129078) {
            int j = u - 129024;
            bias54[j] = (j < 27) ? b_off1[j] : b_off2[j - 27];
        }
    }
}

// ---------- conv3x3 CIN=32 (offset conv), LDS-staged window, 4 waves; om out fp16 ----------
__global__ __launch_bounds__(256, 4) void conv_stage32(
    const unsigned short* __restrict__ xn, const unsigned short* __restrict__ wf,
    const float* __restrict__ bias, unsigned short* __restrict__ out)
{
    __shared__ __align__(16) unsigned short stage[198 * 32];   // 3x66 px x 32ch
    int lb = ((blockIdx.x & 7) << 7) | (blockIdx.x >> 3);
    int t = threadIdx.x;
    int pxbase = lb * 64;
    int b = pxbase >> 14;
    int pbase = pxbase & 16383;
    int rowbase = pbase >> 7, colbase = pbase & 127;
    const unsigned short* xb = xn + ((size_t)(b << 14)) * 32;

    for (int q = t; q < 792; q += 256) {
        int ps = q >> 2, j = q & 3;
        int ly = ps / 66, lx = ps - ly * 66;
        int y = rowbase - 1 + ly, x = colbase - 1 + lx;
        bool ok = (y >= 0) & (y < Hd) & (x >= 0) & (x < Wd);
        u32x4 v = {0, 0, 0, 0};
        if (ok) v = *(const u32x4*)(xb + ((size_t)(y * Wd + x)) * 32 + j * 8);
        *(u32x4*)(stage + ps * 32 + ((j ^ (ps & 3)) << 3)) = v;
    }
    __syncthreads();

    int lane = t & 63, wv = t >> 6;
    int sp = wv * 16 + (lane & 15);
    int px = pxbase + sp;
    int p = px & 16383;
    int cg = lane >> 4;

    const h16x8* wfv = (const h16x8*)wf;
    f32x4 acc[4];
#pragma unroll
    for (int m = 0; m < 4; m++) acc[m] = (f32x4){0.f, 0.f, 0.f, 0.f};

#pragma unroll
    for (int k = 0; k < 9; k++) {
        int ps = (k / 3) * 66 + sp + (k % 3);
        h16x8 bq = *(const h16x8*)(stage + ps * 32 + ((cg ^ (ps & 3)) << 3));
        h16x8 aF[4];
#pragma unroll
        for (int m = 0; m < 4; m++)
            aF[m] = wfv[(k * 4 + m) * 64 + lane];
#pragma unroll
        for (int m = 0; m < 4; m++)
            acc[m] = __builtin_amdgcn_mfma_f32_16x16x32_f16(aF[m], bq, acc[m], 0, 0, 0);
    }

#pragma unroll
    for (int m = 0; m < 4; m++) {
        int ocb = m * 16 + cg * 4;
#pragma unroll
        for (int r = 0; r < 4; r++) {
            int oc = ocb + r;
            if (oc < 54)
                out[((size_t)b * 54 + oc) * HW + p] = f2h(acc[m][r] + bias[oc]);
        }
    }
}

// ---------- conv3x3 CIN=64 (final conv), LDS-staged window, 8 waves kh-split ----------
__global__ __launch_bounds__(512, 8) void conv_stage64(
    const unsigned short* __restrict__ xn, const unsigned short* __restrict__ wf,
    const float* __restrict__ bias, float* __restrict__ out)
{
    __shared__ __align__(16) unsigned short stage[198 * 64];   // 3x66 px x 64ch
    int lb = ((blockIdx.x & 7) << 7) | (blockIdx.x >> 3);
    int t = threadIdx.x;
    int pxbase = lb * 64;
    int b = pxbase >> 14;
    int pbase = pxbase & 16383;
    int rowbase = pbase >> 7, colbase = pbase & 127;
    const unsigned short* xb = xn + ((size_t)(b << 14)) * 64;

    for (int q = t; q < 1584; q += 512) {
        int ps = q >> 3, j = q & 7;
        int ly = ps / 66, lx = ps - ly * 66;
        int y = rowbase - 1 + ly, x = colbase - 1 + lx;
        bool ok = (y >= 0) & (y < Hd) & (x >= 0) & (x < Wd);
        u32x4 v = {0, 0, 0, 0};
        if (ok) v = *(const u32x4*)(xb + ((size_t)(y * Wd + x)) * 64 + j * 8);
        *(u32x4*)(stage + ps * 64 + ((j ^ (ps & 7)) << 3)) = v;
    }
    __syncthreads();

    int lane = t & 63;
    int wave = t >> 6;
    int kh = wave >> 2;
    int wv = wave & 3;
    int sp = wv * 16 + (lane & 15);
    int px = pxbase + sp;
    int p = px & 16383;
    int cg = lane >> 4;
    int cch = kh * 4 + cg;

    const h16x8* wfv = (const h16x8*)wf;
    f32x4 acc[4];
#pragma unroll
    for (int m = 0; m < 4; m++) acc[m] = (f32x4){0.f, 0.f, 0.f, 0.f};

#pragma unroll
    for (int k = 0; k < 9; k++) {
        int ps = (k / 3) * 66 + sp + (k % 3);
        h16x8 bq = *(const h16x8*)(stage + ps * 64 + ((cch ^ (ps & 7)) << 3));
        h16x8 aF[4];
#pragma unroll
        for (int m = 0; m < 4; m++)
            aF[m] = wfv[((k * 4 + m) * 2 + kh) * 64 + lane];
#pragma unroll
        for (int m = 0; m < 4; m++)
            acc[m] = __builtin_amdgcn_mfma_f32_16x16x32_f16(aF[m], bq, acc[m], 0, 0, 0);
    }

    __syncthreads();                 // stage reads done; red aliases stage
    float* red = (float*)stage;
    if (kh == 1) {
#pragma unroll
        for (int m = 0; m < 4; m++)
#pragma unroll
            for (int j = 0; j < 4; j++)
                red[(m * 4 + j) * 256 + wv * 64 + lane] = acc[m][j];
    }
    __syncthreads();
    if (kh == 0) {
#pragma unroll
        for (int m = 0; m < 4; m++) {
            int ocb = m * 16 + cg * 4;
#pragma unroll
            for (int r = 0; r < 4; r++) {
                int oc = ocb + r;
                float v = acc[m][r] + red[(m * 4 + r) * 256 + wv * 64 + lane] + bias[oc];
                out[((size_t)b * 64 + oc) * HW + p] = v;
            }
        }
    }
}

// ---------- DCNv2 sampling helpers ----------
struct Tap { float w00, w01, w10, w11; int o00, o01, o10, o11; };

__device__ inline Tap mkparams(float oy, float ox, float mv, int row, int col, int k) {
    Tap P;
    float mk = 1.f / (1.f + __expf(-mv));
    float ys = (float)(row + k / 3 - 1) + oy;
    float xs = (float)(col + k % 3 - 1) + ox;
    float y0f = floorf(ys), x0f = floorf(xs);
    float fy = ys - y0f, fx = xs - x0f;
    int y0 = (int)y0f, x0 = (int)x0f;
    int y1 = y0 + 1, x1 = x0 + 1;
    bool vy0 = (y0 >= 0) & (y0 < Hd);
    bool vy1 = (y1 >= 0) & (y1 < Hd);
    bool vx0 = (x0 >= 0) & (x0 < Wd);
    bool vx1 = (x1 >= 0) & (x1 < Wd);
    P.w00 = (vy0 && vx0) ? (1.f - fy) * (1.f - fx) * mk : 0.f;
    P.w01 = (vy0 && vx1) ? (1.f - fy) * fx * mk : 0.f;
    P.w10 = (vy1 && vx0) ? fy * (1.f - fx) * mk : 0.f;
    P.w11 = (vy1 && vx1) ? fy * fx * mk : 0.f;
    int iy0 = min(max(y0, 0), Hd - 1) * Wd;
    int iy1 = min(max(y1, 0), Hd - 1) * Wd;
    int ix0 = min(max(x0, 0), Wd - 1);
    int ix1 = min(max(x1, 0), Wd - 1);
    P.o00 = iy0 + ix0; P.o01 = iy0 + ix1; P.o10 = iy1 + ix0; P.o11 = iy1 + ix1;
    return P;
}

// ---------- DCNv2, LDS-staged window; scalar-u32-packed tap tables ----------
// Tables: twp0/twp1 = fp16 weight pairs; tap0/tap1 = addr-code pairs
//   code = fb<<15 | (ps<<3) | (ps&7);  LDS byte addr = ((code&0x7fff)^cch)<<4
// tof[4][] scalar arrays read ONLY in the ~never fallback branch.
// EPI 0: leaky -> outn (NHWC fp16). EPI 1: +resid(NCHW fp32) -> outn (NHWC fp16).
template<int EPI>
__global__ __launch_bounds__(512, 4) void dcn_stage(
    const unsigned short* __restrict__ xn, const unsigned short* __restrict__ omh, int omOff,
    const unsigned short* __restrict__ wf, const float* __restrict__ bias,
    const float* __restrict__ resid, unsigned short* __restrict__ outn)
{
    __shared__ __align__(16) unsigned short stage[490 * 64];  // 7x70 px x 64ch = 62.7KB
    __shared__ unsigned twp0[576], twp1[576];   // fp16 pairs (w00|w01<<16), (w10|w11<<16)
    __shared__ unsigned tap0[576], tap1[576];   // addr codes (a0|a1<<16), (a2|a3<<16)
    __shared__ unsigned short tof[4][576];      // raw corner px idx (fallback only)

    int lb = ((blockIdx.x & 7) << 7) | (blockIdx.x >> 3);
    int t = threadIdx.x;
    int pxbase = lb * 64;
    int b = pxbase >> 14;
    int pbase = pxbase & 16383;
    int rowbase = pbase >> 7;
    int colbase = pbase & 127;
    int ybase = rowbase - 3;
    int xbase = colbase - 3;
    const unsigned short* xb = xn + ((size_t)(b << 14)) * 64;

    // phase 1a: tap params -> scalar-packed tables
    for (int s = t; s < 576; s += 512) {
        int k = s >> 6, sp = s & 63;
        int p = pbase + sp;
        int row = p >> 7, col = p & 127;
        const unsigned short* omb = omh + ((size_t)b * 54 + omOff) * HW + p;
        float oy = h2f(omb[(size_t)(2 * k) * HW]);
        float ox = h2f(omb[(size_t)(2 * k + 1) * HW]);
        float mv = h2f(omb[(size_t)(18 + k) * HW]);
        Tap P = mkparams(oy, ox, mv, row, col, k);

        unsigned a[4];
        int oo[4] = {P.o00, P.o01, P.o10, P.o11};
#pragma unroll
        for (int c = 0; c < 4; c++) {
            int o = oo[c];
            int y = o >> 7, x = o & 127;
            int ly = y - ybase, lx = x - xbase;
            bool inw = ((unsigned)ly < 7u) & ((unsigned)lx < 70u);
            int ps = min(max(ly, 0), 6) * 70 + min(max(lx, 0), 69);
            a[c] = (inw ? 0u : 0x8000u) | (unsigned)((ps << 3) | (ps & 7));
            tof[c][s] = (unsigned short)o;
        }
        twp0[s] = (unsigned)f2h(P.w00) | ((unsigned)f2h(P.w01) << 16);
        twp1[s] = (unsigned)f2h(P.w10) | ((unsigned)f2h(P.w11) << 16);
        tap0[s] = a[0] | (a[1] << 16);
        tap1[s] = a[2] | (a[3] << 16);
    }
    // phase 1b: stage fill, coalesced, chunk-swizzled
    for (int q = t; q < 3920; q += 512) {
        int ps = q >> 3, j = q & 7;
        int ly = ps / 70, lx = ps - ly * 70;
        int y = min(max(ybase + ly, 0), Hd - 1);
        int x = min(max(xbase + lx, 0), Wd - 1);
        u32x4 v = *(const u32x4*)(xb + ((size_t)(y * Wd + x)) * 64 + j * 8);
        *(u32x4*)(stage + ps * 64 + ((j ^ (ps & 7)) << 3)) = v;
    }
    __syncthreads();

    int lane = t & 63;
    int wave = t >> 6;
    int kh = wave >> 2;
    int wv = wave & 3;
    int sp = wv * 16 + (lane & 15);
    int px = pxbase + sp;
    int p = px & 16383;
    int cg = lane >> 4;
    int c0 = kh * 32 + cg * 8;
    int cch = kh * 4 + cg;

    const h16x8* wfv = (const h16x8*)wf;

    f32x4 acc[4];
#pragma unroll
    for (int m = 0; m < 4; m++) acc[m] = (f32x4){0.f, 0.f, 0.f, 0.f};

#pragma unroll
    for (int k = 0; k < 9; k++) {
        int s = k * 64 + sp;
        unsigned a01 = tap0[s], a23 = tap1[s];
        unsigned w01 = twp0[s], w23 = twp1[s];

        unsigned code[4] = { a01 & 0x7fffu, (a01 >> 16) & 0x7fffu,
                             a23 & 0x7fffu, (a23 >> 16) & 0x7fffu };
        h16x8 gc[4];
#pragma unroll
        for (int c = 0; c < 4; c++)
            gc[c] = *(const h16x8*)((const char*)stage + ((code[c] ^ (unsigned)cch) << 4));

        if (__builtin_expect((a01 | a23) & 0x80008000u, 0)) {
            unsigned fb[4] = { a01 & 0x8000u, a01 & 0x80000000u,
                               a23 & 0x8000u, a23 & 0x80000000u };
#pragma unroll
            for (int c = 0; c < 4; c++)
                if (fb[c])
                    gc[c] = *(const h16x8*)(xb + (size_t)tof[c][s] * 64 + c0);
        }

        _Float16 h00 = u2h((unsigned short)(w01 & 0xffffu));
        _Float16 h01 = u2h((unsigned short)(w01 >> 16));
        _Float16 h10 = u2h((unsigned short)(w23 & 0xffffu));
        _Float16 h11 = u2h((unsigned short)(w23 >> 16));
        h16x8 bF = gc[0] * h00;
        bF = gc[1] * h01 + bF;
        bF = gc[2] * h10 + bF;
        bF = gc[3] * h11 + bF;

        h16x8 aF[4];
#pragma unroll
        for (int m = 0; m < 4; m++)
            aF[m] = wfv[((k * 4 + m) * 2 + kh) * 64 + lane];
#pragma unroll
        for (int m = 0; m < 4; m++)
            acc[m] = __builtin_amdgcn_mfma_f32_16x16x32_f16(aF[m], bF, acc[m], 0, 0, 0);
    }

    __syncthreads();
    float* red = (float*)stage;
    if (kh == 1) {
#pragma unroll
        for (int m = 0; m < 4; m++)
#pragma unroll
            for (int j = 0; j < 4; j++)
                red[(m * 4 + j) * 256 + wv * 64 + lane] = acc[m][j];
    }
    __syncthreads();
    if (kh == 0) {
        unsigned short* drow = outn + (size_t)px * 64;
#pragma unroll
        for (int m = 0; m < 4; m++) {
            int ocb = m * 16 + cg * 4;
            unsigned short pk[4];
#pragma unroll
            for (int r = 0; r < 4; r++) {
                int oc = ocb + r;
                float v = acc[m][r] + red[(m * 4 + r) * 256 + wv * 64 + lane] + bias[oc];
                if (EPI == 0) v = (v >= 0.f) ? v : 0.01f * v;
                if (EPI == 1) v += resid[((size_t)b * 64 + oc) * HW + p];
                pk[r] = f2h(v);
            }
            *(ushort4*)(drow + ocb) = *(ushort4*)pk;
        }
    }
}

extern "C" void kernel_launch(void* const* d_in, const int* in_sizes, int n_in,
                              void* d_out, int out_size, void* d_ws, size_t ws_size,
                              hipStream_t stream)
{
    const float* input  = (const float*)d_in[0];
    const float* offset = (const float*)d_in[1];
    const float* w_off1 = (const float*)d_in[2];
    const float* b_off1 = (const float*)d_in[3];
    const float* w1     = (const float*)d_in[4];
    const float* b1     = (const float*)d_in[5];
    const float* w_off2 = (const float*)d_in[6];
    const float* b_off2 = (const float*)d_in[7];
    const float* w2     = (const float*)d_in[8];
    const float* b2     = (const float*)d_in[9];
    const float* w_last = (const float*)d_in[10];
    const float* b_last = (const float*)d_in[11];
    float* out = (float*)d_out;

    float* ws = (float*)d_ws;
    unsigned short* omh = (unsigned short*)ws;             // fp16 om
    unsigned short* xn   = (unsigned short*)(ws + 3538944);   // 4,194,304 ush
    unsigned short* offn = xn + 4194304;                   // 2,097,152 ush
    unsigned short* x1n  = offn + 2097152;                 // 4,194,304 ush
    unsigned short* x2n  = x1n + 4194304;                  // 4,194,304 ush
    unsigned short* wfo  = x2n + 4194304;                  // 18,432 ush
    unsigned short* wf1  = wfo + 18432;                    // 36,864 ush
    unsigned short* wf2  = wf1 + 36864;                    // 36,864 ush
    unsigned short* wfl  = wf2 + 36864;                    // 36,864 ush
    float* bias54 = (float*)(wfl + 36864);                 // 64 f

    prep<<<dim3(1018), 256, 0, stream>>>(input, offset, w_off1, w_off2, b_off1, b_off2,
                                         w1, w2, w_last, xn, offn, wfo, wf1, wf2, wfl, bias54);

    conv_stage32<<<dim3(1024), 256, 0, stream>>>(offn, wfo, bias54, omh);
    dcn_stage<0><<<dim3(1024), 512, 0, stream>>>(xn, omh, 0, wf1, b1, nullptr, x1n);
    dcn_stage<1><<<dim3(1024), 512, 0, stream>>>(x1n, omh, 27, wf2, b2, input, x2n);
    conv_stage64<<<dim3(1024), 512, 0, stream>>>(x2n, wfl, b_last, out);
}

// Round 15
// 79.386 us; speedup vs baseline: 1.8488x; 1.0222x over previous
//
#include <hip/hip_runtime.h>
#include <cmath>

#define HW   16384
#define Wd   128
#define Hd   128
#define NB   4

typedef __attribute__((ext_vector_type(8))) _Float16 h16x8;
typedef __attribute__((ext_vector_type(4))) float f32x4;
typedef __attribute__((ext_vector_type(4))) unsigned int u32x4;

__device__ inline unsigned short f2h(float f) {
    _Float16 h = (_Float16)f;
    return __builtin_bit_cast(unsigned short, h);
}
__device__ inline _Float16 u2h(unsigned short u) {
    return __builtin_bit_cast(_Float16, u);
}

// ---------- fused prep: weight repacks (fp16 MFMA A-frag layout) + bias + NHWC transposes ----------
__device__ inline void repack_one(int idx, const float* __restrict__ s1, const float* __restrict__ s2,
                                  int Osplit, int O, int CIN, int KS, unsigned short* __restrict__ dst) {
    int e    = idx & 7;
    int lane = (idx >> 3) & 63;
    int ks   = (idx >> 9) % KS;
    int m    = (idx / (512 * KS)) & 3;
    int k    = idx / (2048 * KS);
    int oc = m * 16 + (lane & 15);
    int c  = ks * 32 + (lane >> 4) * 8 + e;
    float v = 0.f;
    if (oc < O && c < CIN)
        v = (oc < Osplit) ? s1[((size_t)oc * CIN + c) * 9 + k]
                          : s2[((size_t)(oc - Osplit) * CIN + c) * 9 + k];
    dst[idx] = f2h(v);
}

__global__ __launch_bounds__(256) void prep(
    const float* __restrict__ input, const float* __restrict__ offset,
    const float* __restrict__ w_off1, const float* __restrict__ w_off2,
    const float* __restrict__ b_off1, const float* __restrict__ b_off2,
    const float* __restrict__ w1, const float* __restrict__ w2, const float* __restrict__ w_last,
    unsigned short* __restrict__ xn, unsigned short* __restrict__ offn,
    unsigned short* __restrict__ wfo, unsigned short* __restrict__ wf1,
    unsigned short* __restrict__ wf2, unsigned short* __restrict__ wfl,
    float* __restrict__ bias54)
{
    int blk = blockIdx.x;
    if (blk < 512) {
        int t = blk * 256 + threadIdx.x;
        if (t < 65536) {
            int b = t >> 14, p = t & 16383;
            const float* s = input + ((size_t)b * 64) * HW + p;
            unsigned short* d = xn + (size_t)t * 64;
#pragma unroll
            for (int g = 0; g < 8; g++) {
                unsigned short pk[8];
#pragma unroll
                for (int e = 0; e < 8; e++) pk[e] = f2h(s[(size_t)(g * 8 + e) * HW]);
                *(u32x4*)(d + g * 8) = *(u32x4*)pk;
            }
        } else {
            int u = t - 65536;
            int b = u >> 14, p = u & 16383;
            const float* s = offset + ((size_t)b * 32) * HW + p;
            unsigned short* d = offn + (size_t)u * 32;
#pragma unroll
            for (int g = 0; g < 4; g++) {
                unsigned short pk[8];
#pragma unroll
                for (int e = 0; e < 8; e++) pk[e] = f2h(s[(size_t)(g * 8 + e) * HW]);
                *(u32x4*)(d + g * 8) = *(u32x4*)pk;
            }
        }
    } else {
        int u = (blk - 512) * 256 + threadIdx.x;
        if (u < 18432)        repack_one(u, w_off1, w_off1, 27, 27, 32, 1, wfo);
        else if (u < 36864)   repack_one(u - 18432, w_off2, w_off2, 27, 27, 32, 1, wfo + 18432);
        else if (u < 73728)   repack_one(u - 36864, w1, w1, 64, 64, 64, 2, wf1);
        else if (u < 110592)  repack_one(u - 73728, w2, w2, 64, 64, 64, 2, wf2);
        else if (u < 147456)  repack_one(u - 110592, w_last, w_last, 64, 64, 64, 2, wfl);
        else if (u < 147510) {
            int j = u - 147456;
            bias54[j] = (j < 27) ? b_off1[j] : b_off2[j - 27];
        }
    }
}

// ---------- conv3x3 CIN=64 (final conv), LDS-staged window, 8 waves kh-split ----------
__global__ __launch_bounds__(512, 8) void conv_stage64(
    const unsigned short* __restrict__ xn, const unsigned short* __restrict__ wf,
    const float* __restrict__ bias, float* __restrict__ out)
{
    __shared__ __align__(16) unsigned short stage[198 * 64];   // 3x66 px x 64ch
    int lb = ((blockIdx.x & 7) << 7) | (blockIdx.x >> 3);
    int t = threadIdx.x;
    int pxbase = lb * 64;
    int b = pxbase >> 14;
    int pbase = pxbase & 16383;
    int rowbase = pbase >> 7, colbase = pbase & 127;
    const unsigned short* xb = xn + ((size_t)(b << 14)) * 64;

    for (int q = t; q < 1584; q += 512) {
        int ps = q >> 3, j = q & 7;
        int ly = ps / 66, lx = ps - ly * 66;
        int y = rowbase - 1 + ly, x = colbase - 1 + lx;
        bool ok = (y >= 0) & (y < Hd) & (x >= 0) & (x < Wd);
        u32x4 v = {0, 0, 0, 0};
        if (ok) v = *(const u32x4*)(xb + ((size_t)(y * Wd + x)) * 64 + j * 8);
        *(u32x4*)(stage + ps * 64 + ((j ^ (ps & 7)) << 3)) = v;
    }
    __syncthreads();

    int lane = t & 63;
    int wave = t >> 6;
    int kh = wave >> 2;
    int wv = wave & 3;
    int sp = wv * 16 + (lane & 15);
    int px = pxbase + sp;
    int p = px & 16383;
    int cg = lane >> 4;
    int cch = kh * 4 + cg;

    const h16x8* wfv = (const h16x8*)wf;
    f32x4 acc[4];
#pragma unroll
    for (int m = 0; m < 4; m++) acc[m] = (f32x4){0.f, 0.f, 0.f, 0.f};

#pragma unroll
    for (int k = 0; k < 9; k++) {
        int ps = (k / 3) * 66 + sp + (k % 3);
        h16x8 bq = *(const h16x8*)(stage + ps * 64 + ((cch ^ (ps & 7)) << 3));
        h16x8 aF[4];
#pragma unroll
        for (int m = 0; m < 4; m++)
            aF[m] = wfv[((k * 4 + m) * 2 + kh) * 64 + lane];
#pragma unroll
        for (int m = 0; m < 4; m++)
            acc[m] = __builtin_amdgcn_mfma_f32_16x16x32_f16(aF[m], bq, acc[m], 0, 0, 0);
    }

    __syncthreads();                 // stage reads done; red aliases stage
    float* red = (float*)stage;
    if (kh == 1) {
#pragma unroll
        for (int m = 0; m < 4; m++)
#pragma unroll
            for (int j = 0; j < 4; j++)
                red[(m * 4 + j) * 256 + wv * 64 + lane] = acc[m][j];
    }
    __syncthreads();
    if (kh == 0) {
#pragma unroll
        for (int m = 0; m < 4; m++) {
            int ocb = m * 16 + cg * 4;
#pragma unroll
            for (int r = 0; r < 4; r++) {
                int oc = ocb + r;
                float v = acc[m][r] + red[(m * 4 + r) * 256 + wv * 64 + lane] + bias[oc];
                out[((size_t)b * 64 + oc) * HW + p] = v;
            }
        }
    }
}

// ---------- DCNv2 sampling helpers ----------
struct Tap { float w00, w01, w10, w11; int o00, o01, o10, o11; };

__device__ inline Tap mkparams(float oy, float ox, float mv, int row, int col, int k) {
    Tap P;
    float mk = 1.f / (1.f + __expf(-mv));
    float ys = (float)(row + k / 3 - 1) + oy;
    float xs = (float)(col + k % 3 - 1) + ox;
    float y0f = floorf(ys), x0f = floorf(xs);
    float fy = ys - y0f, fx = xs - x0f;
    int y0 = (int)y0f, x0 = (int)x0f;
    int y1 = y0 + 1, x1 = x0 + 1;
    bool vy0 = (y0 >= 0) & (y0 < Hd);
    bool vy1 = (y1 >= 0) & (y1 < Hd);
    bool vx0 = (x0 >= 0) & (x0 < Wd);
    bool vx1 = (x1 >= 0) & (x1 < Wd);
    P.w00 = (vy0 && vx0) ? (1.f - fy) * (1.f - fx) * mk : 0.f;
    P.w01 = (vy0 && vx1) ? (1.f - fy) * fx * mk : 0.f;
    P.w10 = (vy1 && vx0) ? fy * (1.f - fx) * mk : 0.f;
    P.w11 = (vy1 && vx1) ? fy * fx * mk : 0.f;
    int iy0 = min(max(y0, 0), Hd - 1) * Wd;
    int iy1 = min(max(y1, 0), Hd - 1) * Wd;
    int ix0 = min(max(x0, 0), Wd - 1);
    int ix1 = min(max(x1, 0), Wd - 1);
    P.o00 = iy0 + ix0; P.o01 = iy0 + ix1; P.o10 = iy1 + ix0; P.o11 = iy1 + ix1;
    return P;
}

// ---------- DCNv2 with FUSED offset-conv (27 oc), LDS-staged window ----------
// phase 0: stage offn 3x66 window (aliased in stage), 4 waves run offset conv -> omt (LDS f32)
// phase 1: mkparams from omt -> packed scalar tables; fill main stage; main loop as R14.
// code = inw ? (ps<<3)|(ps&7) : 0x8000|o ;  lds byte = ((code&0xFFF)^cch)<<4 ; fb o = code&0x7fff
// EPI 0: leaky -> outn (NHWC fp16). EPI 1: +resid(NCHW fp32) -> outn (NHWC fp16).
template<int EPI>
__global__ __launch_bounds__(512, 4) void dcn_fused(
    const unsigned short* __restrict__ xn, const unsigned short* __restrict__ offn,
    const unsigned short* __restrict__ wfo, const float* __restrict__ obias,
    const unsigned short* __restrict__ wf, const float* __restrict__ bias,
    const float* __restrict__ resid, unsigned short* __restrict__ outn)
{
    __shared__ __align__(16) unsigned short stage[490 * 64];  // 62.7KB main window
    __shared__ unsigned twp0[576], twp1[576];   // fp16 weight pairs
    __shared__ unsigned tap0[576], tap1[576];   // addr-code pairs

    unsigned short* offstage = stage;           // 198*32 ush = 12672B (dead before main fill)
    float* omt = (float*)(stage + 6336);        // 27*64 f32 = 6912B  (dead before main fill)

    int lb = ((blockIdx.x & 7) << 7) | (blockIdx.x >> 3);
    int t = threadIdx.x;
    int pxbase = lb * 64;
    int b = pxbase >> 14;
    int pbase = pxbase & 16383;
    int rowbase = pbase >> 7;
    int colbase = pbase & 127;
    int ybase = rowbase - 3;
    int xbase = colbase - 3;
    const unsigned short* xb = xn + ((size_t)(b << 14)) * 64;
    const unsigned short* ob = offn + ((size_t)(b << 14)) * 32;

    // ---- phase 0a: stage offn 3x66 window ----
    for (int q = t; q < 792; q += 512) {
        int ps = q >> 2, j = q & 3;
        int ly = ps / 66, lx = ps - ly * 66;
        int y = rowbase - 1 + ly, x = colbase - 1 + lx;
        bool ok = (y >= 0) & (y < Hd) & (x >= 0) & (x < Wd);
        u32x4 v = {0, 0, 0, 0};
        if (ok) v = *(const u32x4*)(ob + ((size_t)(y * Wd + x)) * 32 + j * 8);
        *(u32x4*)(offstage + ps * 32 + ((j ^ (ps & 3)) << 3)) = v;
    }
    __syncthreads();

    int lane = t & 63;
    int wave = t >> 6;

    // ---- phase 0b: offset conv, waves 0-3 (27 oc, m-tiles 0..1) ----
    if (wave < 4) {
        int osp = wave * 16 + (lane & 15);
        int cg4 = lane >> 4;
        const h16x8* wfv = (const h16x8*)wfo;
        f32x4 oacc[2];
#pragma unroll
        for (int m = 0; m < 2; m++) oacc[m] = (f32x4){0.f, 0.f, 0.f, 0.f};
#pragma unroll
        for (int k = 0; k < 9; k++) {
            int ps = (k / 3) * 66 + osp + (k % 3);
            h16x8 bq = *(const h16x8*)(offstage + ps * 32 + ((cg4 ^ (ps & 3)) << 3));
#pragma unroll
            for (int m = 0; m < 2; m++) {
                h16x8 aF = wfv[(k * 4 + m) * 64 + lane];
                oacc[m] = __builtin_amdgcn_mfma_f32_16x16x32_f16(aF, bq, oacc[m], 0, 0, 0);
            }
        }
#pragma unroll
        for (int m = 0; m < 2; m++) {
            int ocb = m * 16 + cg4 * 4;
#pragma unroll
            for (int r = 0; r < 4; r++) {
                int oc = ocb + r;
                if (oc < 27) omt[oc * 64 + osp] = oacc[m][r] + obias[oc];
            }
        }
    }
    __syncthreads();

    // ---- phase 1a: tap params from omt -> packed tables ----
    for (int s = t; s < 576; s += 512) {
        int k = s >> 6, sp2 = s & 63;
        int row = rowbase, col = colbase + sp2;
        float oy = omt[(2 * k) * 64 + sp2];
        float ox = omt[(2 * k + 1) * 64 + sp2];
        float mv = omt[(18 + k) * 64 + sp2];
        Tap P = mkparams(oy, ox, mv, row, col, k);

        unsigned a[4];
        int oo[4] = {P.o00, P.o01, P.o10, P.o11};
#pragma unroll
        for (int c = 0; c < 4; c++) {
            int o = oo[c];
            int y = o >> 7, x = o & 127;
            int ly = y - ybase, lx = x - xbase;
            bool inw = ((unsigned)ly < 7u) & ((unsigned)lx < 70u);
            int ps = min(max(ly, 0), 6) * 70 + min(max(lx, 0), 69);
            a[c] = inw ? (unsigned)((ps << 3) | (ps & 7)) : (0x8000u | (unsigned)o);
        }
        twp0[s] = (unsigned)f2h(P.w00) | ((unsigned)f2h(P.w01) << 16);
        twp1[s] = (unsigned)f2h(P.w10) | ((unsigned)f2h(P.w11) << 16);
        tap0[s] = a[0] | (a[1] << 16);
        tap1[s] = a[2] | (a[3] << 16);
    }
    __syncthreads();   // omt/offstage reads done; safe to overwrite stage

    // ---- phase 1b: fill main 7x70 stage ----
    for (int q = t; q < 3920; q += 512) {
        int ps = q >> 3, j = q & 7;
        int ly = ps / 70, lx = ps - ly * 70;
        int y = min(max(ybase + ly, 0), Hd - 1);
        int x = min(max(xbase + lx, 0), Wd - 1);
        u32x4 v = *(const u32x4*)(xb + ((size_t)(y * Wd + x)) * 64 + j * 8);
        *(u32x4*)(stage + ps * 64 + ((j ^ (ps & 7)) << 3)) = v;
    }
    __syncthreads();

    int kh = wave >> 2;
    int wv = wave & 3;
    int sp = wv * 16 + (lane & 15);
    int px = pxbase + sp;
    int p = px & 16383;
    int cg = lane >> 4;
    int c0 = kh * 32 + cg * 8;
    int cch = kh * 4 + cg;

    const h16x8* wfv = (const h16x8*)wf;

    f32x4 acc[4];
#pragma unroll
    for (int m = 0; m < 4; m++) acc[m] = (f32x4){0.f, 0.f, 0.f, 0.f};

#pragma unroll
    for (int k = 0; k < 9; k++) {
        int s = k * 64 + sp;
        unsigned a01 = tap0[s], a23 = tap1[s];
        unsigned w01 = twp0[s], w23 = twp1[s];

        unsigned code[4] = { a01 & 0xffffu, a01 >> 16, a23 & 0xffffu, a23 >> 16 };
        h16x8 gc[4];
#pragma unroll
        for (int c = 0; c < 4; c++)
            gc[c] = *(const h16x8*)((const char*)stage + (((code[c] & 0xFFFu) ^ (unsigned)cch) << 4));

        if (__builtin_expect((a01 | a23) & 0x80008000u, 0)) {
#pragma unroll
            for (int c = 0; c < 4; c++)
                if (code[c] & 0x8000u)
                    gc[c] = *(const h16x8*)(xb + (size_t)(code[c] & 0x7fffu) * 64 + c0);
        }

        _Float16 h00 = u2h((unsigned short)(w01 & 0xffffu));
        _Float16 h01 = u2h((unsigned short)(w01 >> 16));
        _Float16 h10 = u2h((unsigned short)(w23 & 0xffffu));
        _Float16 h11 = u2h((unsigned short)(w23 >> 16));
        h16x8 bF = gc[0] * h00;
        bF = gc[1] * h01 + bF;
        bF = gc[2] * h10 + bF;
        bF = gc[3] * h11 + bF;

        h16x8 aF[4];
#pragma unroll
        for (int m = 0; m < 4; m++)
            aF[m] = wfv[((k * 4 + m) * 2 + kh) * 64 + lane];
#pragma unroll
        for (int m = 0; m < 4; m++)
            acc[m] = __builtin_amdgcn_mfma_f32_16x16x32_f16(aF[m], bF, acc[m], 0, 0, 0);
    }

    __syncthreads();
    float* red = (float*)stage;
    if (kh == 1) {
#pragma unroll
        for (int m = 0; m < 4; m++)
#pragma unroll
            for (int j = 0; j < 4; j++)
                red[(m * 4 + j) * 256 + wv * 64 + lane] = acc[m][j];
    }
    __syncthreads();
    if (kh == 0) {
        unsigned short* drow = outn + (size_t)px * 64;
#pragma unroll
        for (int m = 0; m < 4; m++) {
            int ocb = m * 16 + cg * 4;
            unsigned short pk[4];
#pragma unroll
            for (int r = 0; r < 4; r++) {
                int oc = ocb + r;
                float v = acc[m][r] + red[(m * 4 + r) * 256 + wv * 64 + lane] + bias[oc];
                if (EPI == 0) v = (v >= 0.f) ? v : 0.01f * v;
                if (EPI == 1) v += resid[((size_t)b * 64 + oc) * HW + p];
                pk[r] = f2h(v);
            }
            *(ushort4*)(drow + ocb) = *(ushort4*)pk;
        }
    }
}

extern "C" void kernel_launch(void* const* d_in, const int* in_sizes, int n_in,
                              void* d_out, int out_size, void* d_ws, size_t ws_size,
                              hipStream_t stream)
{
    const float* input  = (const float*)d_in[0];
    const float* offset = (const float*)d_in[1];
    const float* w_off1 = (const float*)d_in[2];
    const float* b_off1 = (const float*)d_in[3];
    const float* w1     = (const float*)d_in[4];
    const float* b1     = (const float*)d_in[5];
    const float* w_off2 = (const float*)d_in[6];
    const float* b_off2 = (const float*)d_in[7];
    const float* w2     = (const float*)d_in[8];
    const float* b2     = (const float*)d_in[9];
    const float* w_last = (const float*)d_in[10];
    const float* b_last = (const float*)d_in[11];
    float* out = (float*)d_out;

    unsigned short* xn   = (unsigned short*)d_ws;          // 4,194,304 ush
    unsigned short* offn = xn + 4194304;                   // 2,097,152 ush
    unsigned short* x1n  = offn + 2097152;                 // 4,194,304 ush
    unsigned short* x2n  = x1n + 4194304;                  // 4,194,304 ush
    unsigned short* wfo  = x2n + 4194304;                  // 36,864 ush (two 27-oc sets)
    unsigned short* wf1  = wfo + 36864;                    // 36,864 ush
    unsigned short* wf2  = wf1 + 36864;                    // 36,864 ush
    unsigned short* wfl  = wf2 + 36864;                    // 36,864 ush
    float* bias54 = (float*)(wfl + 36864);                 // 64 f

    prep<<<dim3(1089), 256, 0, stream>>>(input, offset, w_off1, w_off2, b_off1, b_off2,
                                         w1, w2, w_last, xn, offn, wfo, wf1, wf2, wfl, bias54);

    // DCN 1 (fused offset-conv set 0): sample xn, leaky -> x1n
    dcn_fused<0><<<dim3(1024), 512, 0, stream>>>(xn, offn, wfo, bias54,
                                                 wf1, b1, nullptr, x1n);
    // DCN 2 (fused offset-conv set 1): sample x1n, + input residual -> x2n
    dcn_fused<1><<<dim3(1024), 512, 0, stream>>>(x1n, offn, wfo + 18432, bias54 + 27,
                                                 wf2, b2, input, x2n);
    // final conv
    conv_stage64<<<dim3(1024), 512, 0, stream>>>(x2n, wfl, b_last, out);
}